// Round 9
// baseline (305.970 us; speedup 1.0000x reference)
//
#include <hip/hip_runtime.h>
#include <hip/hip_fp16.h>

namespace {
constexpr int kB  = 2;
constexpr int kL  = 1024;
constexpr int kDM = 1024;
constexpr int kDI = 2048;
constexpr int kPROJW = 8192;   // proj16 row: [x 0..2048 | z ..4096 | B ..6144 | C ..8192]
constexpr int kBL = 2048;
constexpr int kQ  = 32;        // chunk length
constexpr int kQH = 16;        // rows staged per phase
constexpr int kNC = 32;        // chunks per (b,n)
constexpr int kCvtX = kBL * kDM / 4;      // 524288 vec4
constexpr int kCvtW = 8224 * kDM / 4;     // 2105344 (8192 cvt rows + 32 dt rows -> WdtT)
constexpr int kCvtO = kDM * kDI / 4;      // 524288
constexpr int kCvtBlocks  = (kCvtX + kCvtW + kCvtO) / 256;  // 12320
constexpr int kNegABlocks = 8;
}

typedef float f4 __attribute__((ext_vector_type(4)));
typedef float f2 __attribute__((ext_vector_type(2)));
typedef _Float16 f16x8 __attribute__((ext_vector_type(8)));
typedef _Float16 f16x4 __attribute__((ext_vector_type(4)));
typedef _Float16 f16x2 __attribute__((ext_vector_type(2)));

__device__ __forceinline__ void async_ld16(const void* g, void* l) {
  __builtin_amdgcn_global_load_lds(
      (const __attribute__((address_space(1))) void*)g,
      (__attribute__((address_space(3))) void*)l, 16, 0, 0);
}

__device__ __forceinline__ float sigm(float v) {
  return __builtin_amdgcn_rcpf(1.f + __expf(-v));   // 1-instr rcp vs IEEE div
}

// ---------------------------------------------------------------------------
// K1: f32->f16 cvt of x / W_in(row-permuted) / W_out + WdtT pack + negA.
// ---------------------------------------------------------------------------
__global__ __launch_bounds__(256) void prep_inputs(
    const float* __restrict__ x, const float* __restrict__ W_in,
    const float* __restrict__ W_out, const float* __restrict__ A_log,
    _Float16* __restrict__ x16, _Float16* __restrict__ Wi16,
    _Float16* __restrict__ Wo16, float* __restrict__ WdtT,
    float* __restrict__ negA) {
  const int bid = blockIdx.x;
  const int tid = threadIdx.x;
  if (bid < kCvtBlocks) {
    int i = bid * 256 + tid;
    if (i < kCvtX) {
      const f4 v = ((const f4*)x)[i];
      f16x4 o; o[0]=(_Float16)v[0]; o[1]=(_Float16)v[1]; o[2]=(_Float16)v[2]; o[3]=(_Float16)v[3];
      ((f16x4*)x16)[i] = o;
    } else if (i < kCvtX + kCvtW) {
      i -= kCvtX;
      const int row = i >> 8;        // [0, 8224)
      const int cv  = i & 255;
      if (row < 8192) {
        int srow;
        if (row < 4096)      srow = row;
        else if (row < 6144) { const int m = row - 4096; srow = 4096 + (m >> 6) * 129 + (m & 63); }
        else                 { const int m = row - 6144; srow = 4096 + (m >> 6) * 129 + 64 + (m & 63); }
        const f4 v = ((const f4*)(W_in + (size_t)srow * kDM))[cv];
        f16x4 o; o[0]=(_Float16)v[0]; o[1]=(_Float16)v[1]; o[2]=(_Float16)v[2]; o[3]=(_Float16)v[3];
        ((f16x4*)(Wi16 + (size_t)row * kDM))[cv] = o;
      } else {
        const int h = row - 8192;    // dt row -> transposed f32 pack
        const f4 v = ((const f4*)(W_in + (size_t)(4096 + h * 129 + 128) * kDM))[cv];
        const int k = cv * 4;
        WdtT[(k + 0) * 32 + h] = v[0];
        WdtT[(k + 1) * 32 + h] = v[1];
        WdtT[(k + 2) * 32 + h] = v[2];
        WdtT[(k + 3) * 32 + h] = v[3];
      }
    } else {
      i -= kCvtX + kCvtW;
      const f4 v = ((const f4*)W_out)[i];
      f16x4 o; o[0]=(_Float16)v[0]; o[1]=(_Float16)v[1]; o[2]=(_Float16)v[2]; o[3]=(_Float16)v[3];
      ((f16x4*)Wo16)[i] = o;
    }
  } else {
    const int i = (bid - kCvtBlocks) * 256 + tid;
    if (i < 2048) negA[i] = -__expf(A_log[i]);
  }
}

// ---------------------------------------------------------------------------
// K1b: dtb = softplus(x @ Wdt^T + bias), f32 exact.
// ---------------------------------------------------------------------------
__global__ __launch_bounds__(256) void dt_gemm(
    const float* __restrict__ x, const float* __restrict__ WdtT,
    const float* __restrict__ dt_bias, float* __restrict__ dtb) {
  __shared__ alignas(16) float Xs[4][1024];   // 16 KB
  __shared__ float Ps[4][8][32];              // 4 KB
  const int tid = threadIdx.x;
  const int gm0 = blockIdx.x * 4;
#pragma unroll
  for (int q = 0; q < 4; ++q)
    *(f4*)&Xs[q][tid * 4 - (tid >> 8)] = *(const f4*)(x + (size_t)(gm0 + q) * kDM + tid * 4);
  __syncthreads();

  const int h  = tid & 31;
  const int sl = tid >> 5;
  const int k0 = sl * 128;
  float p0 = 0.f, p1 = 0.f, p2 = 0.f, p3 = 0.f;
#pragma unroll 8
  for (int i = 0; i < 128; ++i) {
    const float w = WdtT[(k0 + i) * 32 + h];
    p0 = fmaf(Xs[0][k0 + i], w, p0);
    p1 = fmaf(Xs[1][k0 + i], w, p1);
    p2 = fmaf(Xs[2][k0 + i], w, p2);
    p3 = fmaf(Xs[3][k0 + i], w, p3);
  }
  Ps[0][sl][h] = p0; Ps[1][sl][h] = p1; Ps[2][sl][h] = p2; Ps[3][sl][h] = p3;
  __syncthreads();
  if (tid < 128) {
    const int r = tid >> 5, hh = tid & 31;
    float v = 0.f;
#pragma unroll
    for (int s2 = 0; s2 < 8; ++s2) v += Ps[r][s2][hh];
    const float dtp = v + dt_bias[hh];
    const float dt  = (dtp > 20.f) ? dtp : log1pf(__expf(dtp));
    const int gm = gm0 + r;
    dtb[(size_t)((gm >> 10) * 32 + hh) * kL + (gm & 1023)] = dt;
  }
}

// ---------------------------------------------------------------------------
// K2: f16 GEMM 128x128, BK=32, dbuf prefetch, XCD swizzle.
// LDS XOR-swizzle (rule #21): linear LDS dest + swizzled GLOBAL src chunk
// (phys_chunk = logical ^ ((row>>1)&3)) + same XOR on the ds_read side.
// Spreads each 16-lane group over all 8 16B slots / 128B -> 2-way (free).
// ---------------------------------------------------------------------------
__global__ __launch_bounds__(256) void gemm1(
    const _Float16* __restrict__ A, const _Float16* __restrict__ Bm,
    _Float16* __restrict__ C, int M, int N, int K) {
  __shared__ alignas(16) _Float16 As[2][128][32];
  __shared__ alignas(16) _Float16 Bs[2][128][32];
  const int tid  = threadIdx.x;
  const int lane = tid & 63;
  const int w    = tid >> 6;
  const int id   = blockIdx.x;
  const int sw   = (id & 7) * 128 + (id >> 3);   // XCD swizzle (nwg=1024)
  const int m0   = (sw & 15) * 128;              // M/128 = 16 tiles
  const int n0   = (sw >> 4) * 128;
  const int ra   = lane >> 2;
  const int cc   = (lane & 3) * 8;                             // linear LDS chunk
  const int ccs  = (((lane & 3) ^ ((lane >> 3) & 3))) * 8;     // swizzled global chunk
  const int wm   = (w & 1) * 64;
  const int wn   = (w >> 1) * 64;
  const int l16  = lane & 15;
  const int l4   = lane >> 4;
  const int rsw  = (l16 >> 1) & 3;                             // read-side XOR

  f4 acc[4][4] = {};

  auto stage = [&](int buf, int k0) {
#pragma unroll
    for (int q = 0; q < 2; ++q) {
      const int row = (w * 2 + q) * 16 + ra;
      async_ld16(A + (size_t)(m0 + row) * K + (k0 + ccs), &As[buf][row][cc]);
      async_ld16(Bm + (size_t)(n0 + row) * K + (k0 + ccs), &Bs[buf][row][cc]);
    }
  };
  auto compute = [&](int buf) {
    f16x8 af[4], bf[4];
#pragma unroll
    for (int t = 0; t < 4; ++t) {
      af[t] = *reinterpret_cast<const f16x8*>(&As[buf][wm + t * 16 + l16][(l4 ^ rsw) * 8]);
      bf[t] = *reinterpret_cast<const f16x8*>(&Bs[buf][wn + t * 16 + l16][(l4 ^ rsw) * 8]);
    }
#pragma unroll
    for (int i = 0; i < 4; ++i)
#pragma unroll
      for (int j = 0; j < 4; ++j)
        acc[i][j] = __builtin_amdgcn_mfma_f32_16x16x32_f16(af[i], bf[j], acc[i][j], 0, 0, 0);
  };

  stage(0, 0);
  __syncthreads();
  int cur = 0;
  for (int k0 = 0; k0 < K - 32; k0 += 32) {
    stage(cur ^ 1, k0 + 32);   // next tile in flight during compute
    compute(cur);
    __syncthreads();           // drains vmcnt(0): next buffer ready
    cur ^= 1;
  }
  compute(cur);                // last tile, no prefetch

  const int col = l16;      // C/D: col = lane&15, row = (lane>>4)*4 + reg
  const int r0  = l4 * 4;
#pragma unroll
  for (int i = 0; i < 4; ++i)
#pragma unroll
    for (int j = 0; j < 4; ++j) {
      const int gn = n0 + wn + j * 16 + col;
#pragma unroll
      for (int r = 0; r < 4; ++r) {
        const int gm = m0 + wm + i * 16 + r0 + r;
        C[(size_t)gm * N + gn] = (_Float16)acc[i][j][r];
      }
    }
}

// ---------------------------------------------------------------------------
// K3: scan pass 1. 2 heads per 256-thr block; all-f32 LDS; 2-d-per-lane.
// Unchanged from R8 (measured improvement).
// ---------------------------------------------------------------------------
__global__ __launch_bounds__(256) void scan_pass1(
    const _Float16* __restrict__ proj16, const float* __restrict__ dtb,
    const float* __restrict__ negA, const float* __restrict__ conv_w,
    const float* __restrict__ conv_b, float* __restrict__ H,
    float* __restrict__ sdt) {
  __shared__ alignas(16) float Ad[2][kQH][64];   // 8 KB
  __shared__ alignas(16) float Bd[2][kQH][64];   // 8 KB
  __shared__ alignas(16) float Xd[2][kQH][64];   // 8 KB (xdt f32)
  __shared__ float dts[2][kQ];
  const int tid  = threadIdx.x;
  const int g    = blockIdx.x;
  const int c    = g & (kNC - 1);
  const int bnp  = g >> 5;
  const int lane = tid & 63;
  const int w    = tid >> 6;
  const int hb   = w >> 1;
  const int wd   = w & 1;
  const int sg   = lane >> 4;
  const int dd   = lane & 15;
  const int bn   = bnp * 2 + hb;
  const int b    = bn >> 5, n = bn & 31;
  const int l0   = c * kQ;
  const int d0   = wd * 32 + dd * 2;
  const int t128 = tid & 127;
  const int shb  = tid >> 7;   // staging: which head this thread serves

  f4 hA[4] = {}, hB[4] = {};

  for (int p = 0; p < 2; ++p) {
    const int r0 = p * kQH;
    // ---- stage (128 thr per head): row = t128>>3, 8-ch slice ----
    {
      const int sn  = (bnp * 2 + shb) & 31;
      const int sb  = (bnp * 2 + shb) >> 5;
      const int row = t128 >> 3;
      const int ch  = (t128 & 7) * 8;
      const int gl  = l0 + r0 + row;
      const float dtl = dtb[(size_t)(bnp * 2 + shb) * kL + gl];
      if ((t128 & 7) == 0) dts[shb][r0 + row] = dtl;
      // B: f16 -> f32
      const f16x8 vb = *(const f16x8*)(proj16 +
          (size_t)(sb * kL + gl) * kPROJW + 4096 + sn * 64 + ch);
      f4 blo, bhi;
      blo[0]=(float)vb[0]; blo[1]=(float)vb[1]; blo[2]=(float)vb[2]; blo[3]=(float)vb[3];
      bhi[0]=(float)vb[4]; bhi[1]=(float)vb[5]; bhi[2]=(float)vb[6]; bhi[3]=(float)vb[7];
      *(f4*)&Bd[shb][row][ch]     = blo;
      *(f4*)&Bd[shb][row][ch + 4] = bhi;
      // A: exp
#pragma unroll
      for (int j = 0; j < 8; ++j)
        Ad[shb][row][ch + j] = __expf(negA[sn * 64 + ch + j] * dtl);
      // conv + silu -> xdt (f32)
      float acc[8];
#pragma unroll
      for (int j = 0; j < 8; ++j) acc[j] = conv_b[sn * 64 + ch + j];
#pragma unroll
      for (int jj = 0; jj < 4; ++jj) {
        const int r = gl - 3 + jj;
        if (r < 0) continue;
        const f16x8 v0 = *(const f16x8*)(proj16 + (size_t)(sb * kL + r) * kPROJW + sn * 64 + ch);
#pragma unroll
        for (int j = 0; j < 8; ++j)
          acc[j] += conv_w[(sn * 64 + ch + j) * 4 + jj] * (float)v0[j];
      }
#pragma unroll
      for (int j = 0; j < 8; ++j)
        Xd[shb][row][ch + j] = dtl * (acc[j] * sigm(acc[j]));
    }
    __syncthreads();

    // ---- compute ----
#pragma unroll 2
    for (int tt = 0; tt < kQH; ++tt) {
      const f2 xv = *(const f2*)&Xd[hb][tt][d0];
      const float x0 = xv[0], x1 = xv[1];
#pragma unroll
      for (int q = 0; q < 4; ++q) {
        const f4 a  = ((const f4*)&Ad[hb][tt][sg * 16])[q];
        const f4 bb = ((const f4*)&Bd[hb][tt][sg * 16])[q];
        hA[q] = a * hA[q] + bb * x0;
        hB[q] = a * hB[q] + bb * x1;
      }
    }
    __syncthreads();
  }

  if (t128 == 0) {     // tid 0 -> head 0, tid 128 -> head 1
    float s = 0.f;
    for (int t = 0; t < kQ; ++t) s += dts[shb][t];
    sdt[(bnp * 2 + shb) * kNC + c] = s;
  }

  float* hp = H + (((size_t)bn * kNC + c) * 64 + sg * 16) * 64 + d0;
#pragma unroll
  for (int q = 0; q < 4; ++q)
#pragma unroll
    for (int i = 0; i < 4; ++i) {
      f2 hv; hv[0] = hA[q][i]; hv[1] = hB[q][i];
      *(f2*)&hp[(size_t)(q * 4 + i) * 64] = hv;
    }
}

// ---------------------------------------------------------------------------
// K4: chunk stitching IN-PLACE: H[c] holds local sums on entry, carry-in
// h_in[c] on exit. h_in[c+1] = exp(negA_s*sdt[c])*h_in[c] + hloc[c].
// ---------------------------------------------------------------------------
__global__ __launch_bounds__(256) void scan_pass2(
    float* __restrict__ H, const float* __restrict__ sdt,
    const float* __restrict__ negA) {
  const int bn = blockIdx.x >> 2;
  const int dq = blockIdx.x & 3;
  const int n  = bn & 31;
  const int s  = threadIdx.x >> 2;
  const int d0 = dq * 16 + (threadIdx.x & 3) * 4;
  const float Aa = negA[n * 64 + s];
  f4 h = {};
  for (int c = 0; c < kNC; ++c) {
    const size_t off = (((size_t)bn * kNC + c) * 64 + s) * 64 + d0;
    const float ap = __expf(Aa * sdt[bn * kNC + c]);
    const f4 hl = *(const f4*)(H + off);   // local sums
    *(f4*)(H + off) = h;                   // overwrite with carry-in
    h = ap * h + hl;
  }
}

// ---------------------------------------------------------------------------
// K5: scan pass 3. 2-head packing, all-f32 A/B/C/X LDS. Unchanged from R8.
// ---------------------------------------------------------------------------
__global__ __launch_bounds__(256) void scan_pass3(
    const _Float16* __restrict__ proj16, const float* __restrict__ dtb,
    const float* __restrict__ negA, const float* __restrict__ conv_w,
    const float* __restrict__ conv_b, const float* __restrict__ H,
    const float* __restrict__ Dv, _Float16* __restrict__ yin) {
  __shared__ alignas(16) float Ad[2][kQH][64];     // 8 KB
  __shared__ alignas(16) float Bd[2][kQH][64];     // 8 KB
  __shared__ alignas(16) float Cd[2][kQH][64];     // 8 KB
  __shared__ alignas(16) float Xd[2][kQH][64];     // 8 KB (xdt f32)
  __shared__ alignas(16) _Float16 Xs[2][kQH][64];  // 2 KB (xsilu f16)
  __shared__ alignas(16) _Float16 Zd[2][kQH][64];  // 2 KB (raw z)
  const int tid  = threadIdx.x;
  const int g    = blockIdx.x;
  const int c    = g & (kNC - 1);
  const int bnp  = g >> 5;
  const int lane = tid & 63;
  const int w    = tid >> 6;
  const int hb   = w >> 1;
  const int wd   = w & 1;
  const int sg   = lane >> 4;
  const int dd   = lane & 15;
  const int bn   = bnp * 2 + hb;
  const int b    = bn >> 5, n = bn & 31;
  const int l0   = c * kQ;
  const int d0   = wd * 32 + dd * 2;
  const int t128 = tid & 127;
  const int shb  = tid >> 7;

  // h init from carry-in (registers, carried across both phases)
  f4 hA[4], hB[4];
  {
    const float* hp = H + (((size_t)bn * kNC + c) * 64 + sg * 16) * 64 + d0;
#pragma unroll
    for (int q = 0; q < 4; ++q)
#pragma unroll
      for (int i = 0; i < 4; ++i) {
        const f2 hv = *(const f2*)&hp[(size_t)(q * 4 + i) * 64];
        hA[q][i] = hv[0]; hB[q][i] = hv[1];
      }
  }
  const float Dn = Dv[n];
  _Float16* Yb = yin + (size_t)(b * kL + l0) * kDI + n * 64 + d0;

  for (int p = 0; p < 2; ++p) {
    const int r0 = p * kQH;
    // ---- stage (128 thr per head) ----
    {
      const int sn  = (bnp * 2 + shb) & 31;
      const int sb  = (bnp * 2 + shb) >> 5;
      const int row = t128 >> 3;
      const int ch  = (t128 & 7) * 8;
      const int gl  = l0 + r0 + row;
      const _Float16* base = proj16 + (size_t)(sb * kL + gl) * kPROJW + sn * 64 + ch;
      async_ld16(base + 2048, &Zd[shb][row][ch]);
      const float dtl = dtb[(size_t)(bnp * 2 + shb) * kL + gl];
      // B, C: f16 -> f32
      const f16x8 vb = *(const f16x8*)(base + 4096);
      const f16x8 vc = *(const f16x8*)(base + 6144);
      f4 blo, bhi, clo, chi;
      blo[0]=(float)vb[0]; blo[1]=(float)vb[1]; blo[2]=(float)vb[2]; blo[3]=(float)vb[3];
      bhi[0]=(float)vb[4]; bhi[1]=(float)vb[5]; bhi[2]=(float)vb[6]; bhi[3]=(float)vb[7];
      clo[0]=(float)vc[0]; clo[1]=(float)vc[1]; clo[2]=(float)vc[2]; clo[3]=(float)vc[3];
      chi[0]=(float)vc[4]; chi[1]=(float)vc[5]; chi[2]=(float)vc[6]; chi[3]=(float)vc[7];
      *(f4*)&Bd[shb][row][ch]     = blo;
      *(f4*)&Bd[shb][row][ch + 4] = bhi;
      *(f4*)&Cd[shb][row][ch]     = clo;
      *(f4*)&Cd[shb][row][ch + 4] = chi;
      // A: exp
#pragma unroll
      for (int j = 0; j < 8; ++j)
        Ad[shb][row][ch + j] = __expf(negA[sn * 64 + ch + j] * dtl);
      // conv + silu -> xsilu (f16) and xdt (f32)
      float acc[8];
#pragma unroll
      for (int j = 0; j < 8; ++j) acc[j] = conv_b[sn * 64 + ch + j];
#pragma unroll
      for (int jj = 0; jj < 4; ++jj) {
        const int r = gl - 3 + jj;
        if (r < 0) continue;
        const f16x8 v0 = *(const f16x8*)(proj16 + (size_t)(sb * kL + r) * kPROJW + sn * 64 + ch);
#pragma unroll
        for (int j = 0; j < 8; ++j)
          acc[j] += conv_w[(sn * 64 + ch + j) * 4 + jj] * (float)v0[j];
      }
      f16x8 xo;
#pragma unroll
      for (int j = 0; j < 8; ++j) {
        const float xs = acc[j] * sigm(acc[j]);
        xo[j] = (_Float16)xs;
        Xd[shb][row][ch + j] = dtl * xs;
      }
      *(f16x8*)&Xs[shb][row][ch] = xo;
    }
    __syncthreads();

    // ---- compute ----
#pragma unroll 2
    for (int tt = 0; tt < kQH; ++tt) {
      const f2 xv = *(const f2*)&Xd[hb][tt][d0];
      const float x0 = xv[0], x1 = xv[1];
      f4 pvA = {}, pvB = {};
#pragma unroll
      for (int q = 0; q < 4; ++q) {
        const f4 a  = ((const f4*)&Ad[hb][tt][sg * 16])[q];
        const f4 bb = ((const f4*)&Bd[hb][tt][sg * 16])[q];
        const f4 cc = ((const f4*)&Cd[hb][tt][sg * 16])[q];
        hA[q] = a * hA[q] + bb * x0;
        hB[q] = a * hB[q] + bb * x1;
        pvA = pvA + cc * hA[q];
        pvB = pvB + cc * hB[q];
      }
      float pA = (pvA[0] + pvA[1]) + (pvA[2] + pvA[3]);
      float pB = (pvB[0] + pvB[1]) + (pvB[2] + pvB[3]);
      pA += __shfl_xor(pA, 16);
      pA += __shfl_xor(pA, 32);
      pB += __shfl_xor(pB, 16);
      pB += __shfl_xor(pB, 32);
      if (sg == 0) {
        const f16x2 zv = *(const f16x2*)&Zd[hb][tt][d0];
        const f16x2 xs = *(const f16x2*)&Xs[hb][tt][d0];
        const float z0 = (float)zv[0], z1 = (float)zv[1];
        const float y0 = (pA + Dn * (float)xs[0]) * (z0 * sigm(z0));
        const float y1 = (pB + Dn * (float)xs[1]) * (z1 * sigm(z1));
        f16x2 yv; yv[0] = (_Float16)y0; yv[1] = (_Float16)y1;
        *(f16x2*)&Yb[(size_t)(r0 + tt) * kDI] = yv;
      }
    }
    __syncthreads();
  }
}

// ---------------------------------------------------------------------------
// K6: out[2048,1024] f32 = yin @ Wo16^T. 64x64 tile, BK=32, dbuf prefetch,
// XCD swizzle (nwg=512), same XOR-swizzle as gemm1.
// ---------------------------------------------------------------------------
__global__ __launch_bounds__(256) void gemm_out(
    const _Float16* __restrict__ A, const _Float16* __restrict__ Bm,
    float* __restrict__ C) {
  __shared__ alignas(16) _Float16 As[2][64][32];
  __shared__ alignas(16) _Float16 Bs[2][64][32];
  const int tid  = threadIdx.x;
  const int lane = tid & 63;
  const int w    = tid >> 6;
  const int id   = blockIdx.x;
  const int sw   = (id & 7) * 64 + (id >> 3);    // XCD swizzle (nwg=512)
  const int m0   = (sw >> 4) * 64;               // 32 M-tiles
  const int n0   = (sw & 15) * 64;               // 16 N-tiles
  const int row  = tid >> 2;
  const int cc   = (tid & 3) * 8;                          // linear LDS chunk
  const int ccs  = (((lane & 3) ^ ((lane >> 3) & 3))) * 8; // swizzled global chunk
  const int wm   = (w & 1) * 32;
  const int wn   = (w >> 1) * 32;
  const int l16  = lane & 15;
  const int l4   = lane >> 4;
  const int rsw  = (l16 >> 1) & 3;                         // read-side XOR

  f4 acc[2][2] = {};

  auto stage = [&](int buf, int k0) {
    async_ld16(A + (size_t)(m0 + row) * kDI + (k0 + ccs), &As[buf][row][cc]);
    async_ld16(Bm + (size_t)(n0 + row) * kDI + (k0 + ccs), &Bs[buf][row][cc]);
  };
  auto compute = [&](int buf) {
    f16x8 af[2], bf[2];
#pragma unroll
    for (int t = 0; t < 2; ++t) {
      af[t] = *reinterpret_cast<const f16x8*>(&As[buf][wm + t * 16 + l16][(l4 ^ rsw) * 8]);
      bf[t] = *reinterpret_cast<const f16x8*>(&Bs[buf][wn + t * 16 + l16][(l4 ^ rsw) * 8]);
    }
#pragma unroll
    for (int i = 0; i < 2; ++i)
#pragma unroll
      for (int j = 0; j < 2; ++j)
        acc[i][j] = __builtin_amdgcn_mfma_f32_16x16x32_f16(af[i], bf[j], acc[i][j], 0, 0, 0);
  };

  stage(0, 0);
  __syncthreads();
  int cur = 0;
  for (int k0 = 0; k0 < kDI - 32; k0 += 32) {
    stage(cur ^ 1, k0 + 32);
    compute(cur);
    __syncthreads();
    cur ^= 1;
  }
  compute(cur);

  const int col = l16;
  const int r0  = l4 * 4;
#pragma unroll
  for (int i = 0; i < 2; ++i)
#pragma unroll
    for (int j = 0; j < 2; ++j) {
      const int gn = n0 + wn + j * 16 + col;
#pragma unroll
      for (int r = 0; r < 4; ++r) {
        const int gm = m0 + wm + i * 16 + r0 + r;
        C[(size_t)gm * kDM + gn] = acc[i][j][r];
      }
    }
}

// ---------------------------------------------------------------------------
extern "C" void kernel_launch(void* const* d_in, const int* in_sizes, int n_in,
                              void* d_out, int out_size, void* d_ws, size_t ws_size,
                              hipStream_t stream) {
  const float* x      = (const float*)d_in[0];
  const float* W_in   = (const float*)d_in[1];
  const float* conv_w = (const float*)d_in[2];
  const float* conv_b = (const float*)d_in[3];
  const float* A_log  = (const float*)d_in[4];
  const float* Dv     = (const float*)d_in[5];
  const float* dt_b   = (const float*)d_in[6];
  const float* W_out  = (const float*)d_in[7];
  float* out = (float*)d_out;

  char* p = (char*)d_ws;
  _Float16* proj16 = (_Float16*)p; p += (size_t)kBL * kPROJW * 2;   // 33.6 MB
  float* dtb   = (float*)p; p += (size_t)64 * kL * 4;
  float* negA  = (float*)p; p += 2048 * 4;
  float* WdtT  = (float*)p; p += (size_t)1024 * 32 * 4;             // 128 KB
  float* sdt   = (float*)p; p += (size_t)64 * kNC * 4 + 3968;       // 8 KB + pad
  float* H     = (float*)p; p += (size_t)64 * kNC * 64 * 64 * 4;    // 33.6 MB (local sums -> carry-ins, in place)
  _Float16* yin  = (_Float16*)p; p += (size_t)kBL * kDI * 2;        // 8.4 MB
  _Float16* Wo16 = (_Float16*)p; p += (size_t)kDM * kDI * 2;        // 4.2 MB
  _Float16* x16  = (_Float16*)H;                    // alias (pre-scan phase)
  _Float16* Wi16 = x16 + (size_t)kBL * kDM;         // 16.8 MB, fits in H (33.6)

  prep_inputs<<<kCvtBlocks + kNegABlocks, 256, 0, stream>>>(
      x, W_in, W_out, A_log, x16, Wi16, Wo16, WdtT, negA);

  dt_gemm<<<kBL / 4, 256, 0, stream>>>(x, WdtT, dt_b, dtb);

  gemm1<<<(kBL / 128) * (kPROJW / 128), 256, 0, stream>>>(
      x16, Wi16, proj16, kBL, kPROJW, kDM);

  scan_pass1<<<(64 / 2) * kNC, 256, 0, stream>>>(proj16, dtb, negA, conv_w, conv_b, H, sdt);
  scan_pass2<<<256, 256, 0, stream>>>(H, sdt, negA);
  scan_pass3<<<(64 / 2) * kNC, 256, 0, stream>>>(proj16, dtb, negA, conv_w, conv_b, H, Dv, yin);

  gemm_out<<<(kBL / 64) * (kDM / 64), 256, 0, stream>>>(yin, Wo16, out);
}

// Round 10
// 294.020 us; speedup vs baseline: 1.0406x; 1.0406x over previous
//
#include <hip/hip_runtime.h>
#include <hip/hip_fp16.h>

namespace {
constexpr int kB  = 2;
constexpr int kL  = 1024;
constexpr int kDM = 1024;
constexpr int kDI = 2048;
constexpr int kPROJW = 8192;   // proj16 row: [x 0..2048 | z ..4096 | B ..6144 | C ..8192]
constexpr int kBL = 2048;
constexpr int kQ  = 32;        // chunk length
constexpr int kQH = 16;        // rows staged per phase
constexpr int kNC = 32;        // chunks per (b,n)
constexpr int kCvtX = kBL * kDM / 4;      // 524288 vec4
constexpr int kCvtW = 8224 * kDM / 4;     // 2105344 (8192 cvt rows + 32 dt rows -> WdtT)
constexpr int kCvtO = kDM * kDI / 4;      // 524288
constexpr int kCvtBlocks  = (kCvtX + kCvtW + kCvtO) / 256;  // 12320
constexpr int kNegABlocks = 8;
}

typedef float f4 __attribute__((ext_vector_type(4)));
typedef float f2 __attribute__((ext_vector_type(2)));
typedef _Float16 f16x8 __attribute__((ext_vector_type(8)));
typedef _Float16 f16x4 __attribute__((ext_vector_type(4)));
typedef _Float16 f16x2 __attribute__((ext_vector_type(2)));

__device__ __forceinline__ void async_ld16(const void* g, void* l) {
  __builtin_amdgcn_global_load_lds(
      (const __attribute__((address_space(1))) void*)g,
      (__attribute__((address_space(3))) void*)l, 16, 0, 0);
}

__device__ __forceinline__ float sigm(float v) {
  return __builtin_amdgcn_rcpf(1.f + __expf(-v));   // 1-instr rcp vs IEEE div
}

// ---------------------------------------------------------------------------
// K1: f32->f16 cvt of x / W_in(row-permuted) / W_out + WdtT pack + negA.
// ---------------------------------------------------------------------------
__global__ __launch_bounds__(256) void prep_inputs(
    const float* __restrict__ x, const float* __restrict__ W_in,
    const float* __restrict__ W_out, const float* __restrict__ A_log,
    _Float16* __restrict__ x16, _Float16* __restrict__ Wi16,
    _Float16* __restrict__ Wo16, float* __restrict__ WdtT,
    float* __restrict__ negA) {
  const int bid = blockIdx.x;
  const int tid = threadIdx.x;
  if (bid < kCvtBlocks) {
    int i = bid * 256 + tid;
    if (i < kCvtX) {
      const f4 v = ((const f4*)x)[i];
      f16x4 o; o[0]=(_Float16)v[0]; o[1]=(_Float16)v[1]; o[2]=(_Float16)v[2]; o[3]=(_Float16)v[3];
      ((f16x4*)x16)[i] = o;
    } else if (i < kCvtX + kCvtW) {
      i -= kCvtX;
      const int row = i >> 8;        // [0, 8224)
      const int cv  = i & 255;
      if (row < 8192) {
        int srow;
        if (row < 4096)      srow = row;
        else if (row < 6144) { const int m = row - 4096; srow = 4096 + (m >> 6) * 129 + (m & 63); }
        else                 { const int m = row - 6144; srow = 4096 + (m >> 6) * 129 + 64 + (m & 63); }
        const f4 v = ((const f4*)(W_in + (size_t)srow * kDM))[cv];
        f16x4 o; o[0]=(_Float16)v[0]; o[1]=(_Float16)v[1]; o[2]=(_Float16)v[2]; o[3]=(_Float16)v[3];
        ((f16x4*)(Wi16 + (size_t)row * kDM))[cv] = o;
      } else {
        const int h = row - 8192;    // dt row -> transposed f32 pack
        const f4 v = ((const f4*)(W_in + (size_t)(4096 + h * 129 + 128) * kDM))[cv];
        const int k = cv * 4;
        WdtT[(k + 0) * 32 + h] = v[0];
        WdtT[(k + 1) * 32 + h] = v[1];
        WdtT[(k + 2) * 32 + h] = v[2];
        WdtT[(k + 3) * 32 + h] = v[3];
      }
    } else {
      i -= kCvtX + kCvtW;
      const f4 v = ((const f4*)W_out)[i];
      f16x4 o; o[0]=(_Float16)v[0]; o[1]=(_Float16)v[1]; o[2]=(_Float16)v[2]; o[3]=(_Float16)v[3];
      ((f16x4*)Wo16)[i] = o;
    }
  } else {
    const int i = (bid - kCvtBlocks) * 256 + tid;
    if (i < 2048) negA[i] = -__expf(A_log[i]);
  }
}

// ---------------------------------------------------------------------------
// K1b: dtb = softplus(x @ Wdt^T + bias), f32 exact.
// ---------------------------------------------------------------------------
__global__ __launch_bounds__(256) void dt_gemm(
    const float* __restrict__ x, const float* __restrict__ WdtT,
    const float* __restrict__ dt_bias, float* __restrict__ dtb) {
  __shared__ alignas(16) float Xs[4][1024];   // 16 KB
  __shared__ float Ps[4][8][32];              // 4 KB
  const int tid = threadIdx.x;
  const int gm0 = blockIdx.x * 4;
#pragma unroll
  for (int q = 0; q < 4; ++q)
    *(f4*)&Xs[q][tid * 4 - (tid >> 8)] = *(const f4*)(x + (size_t)(gm0 + q) * kDM + tid * 4);
  __syncthreads();

  const int h  = tid & 31;
  const int sl = tid >> 5;
  const int k0 = sl * 128;
  float p0 = 0.f, p1 = 0.f, p2 = 0.f, p3 = 0.f;
#pragma unroll 8
  for (int i = 0; i < 128; ++i) {
    const float w = WdtT[(k0 + i) * 32 + h];
    p0 = fmaf(Xs[0][k0 + i], w, p0);
    p1 = fmaf(Xs[1][k0 + i], w, p1);
    p2 = fmaf(Xs[2][k0 + i], w, p2);
    p3 = fmaf(Xs[3][k0 + i], w, p3);
  }
  Ps[0][sl][h] = p0; Ps[1][sl][h] = p1; Ps[2][sl][h] = p2; Ps[3][sl][h] = p3;
  __syncthreads();
  if (tid < 128) {
    const int r = tid >> 5, hh = tid & 31;
    float v = 0.f;
#pragma unroll
    for (int s2 = 0; s2 < 8; ++s2) v += Ps[r][s2][hh];
    const float dtp = v + dt_bias[hh];
    const float dt  = (dtp > 20.f) ? dtp : log1pf(__expf(dtp));
    const int gm = gm0 + r;
    dtb[(size_t)((gm >> 10) * 32 + hh) * kL + (gm & 1023)] = dt;
  }
}

// ---------------------------------------------------------------------------
// K2: f16 GEMM, BM=128 x BN=256 tile, 512 thr (8 waves), BK=32, dbuf
// prefetch. 2x MFMA per barrier vs 128^2 -> amortizes the vmcnt(0) drain.
// T2 XOR-swizzle kept (stage key (tid>>3)&3 == (row>>1)&3 for A rows tid>>2
// and B rows tid>>2 / tid>>2+128; offset 128 is key-neutral). XCD swizzle:
// nwg=512, cpx=64 -> each XCD sweeps 16 M-tiles x 4 N-tiles (A panel 4MB=L2).
// ---------------------------------------------------------------------------
__global__ __launch_bounds__(512) void gemm1(
    const _Float16* __restrict__ A, const _Float16* __restrict__ Bm,
    _Float16* __restrict__ C, int M, int N, int K) {
  __shared__ alignas(16) _Float16 As[2][128][32];
  __shared__ alignas(16) _Float16 Bs[2][256][32];
  const int tid  = threadIdx.x;      // 0..511
  const int lane = tid & 63;
  const int w    = tid >> 6;         // 0..7
  const int id   = blockIdx.x;
  const int sw   = (id & 7) * 64 + (id >> 3);    // XCD swizzle (nwg=512)
  const int m0   = (sw & 15) * 128;              // 16 M tiles
  const int n0   = (sw >> 4) * 256;              // 32 N tiles
  const int ar   = tid >> 2;                     // staging row 0..127
  const int cc   = (tid & 3) * 8;                            // linear LDS chunk
  const int ccs  = (((tid & 3) ^ ((tid >> 3) & 3))) * 8;     // swizzled global chunk
  const int wm   = (w & 1) * 64;                 // wave M offset (2 x 64)
  const int wn   = (w >> 1) * 64;                // wave N offset (4 x 64)
  const int l16  = lane & 15;
  const int l4   = lane >> 4;
  const int rsw  = (l16 >> 1) & 3;               // read-side XOR key

  f4 acc[4][4] = {};

  auto stage = [&](int buf, int k0) {
    async_ld16(A  + (size_t)(m0 + ar) * K + (k0 + ccs), &As[buf][ar][cc]);
    async_ld16(Bm + (size_t)(n0 + ar) * K + (k0 + ccs), &Bs[buf][ar][cc]);
    async_ld16(Bm + (size_t)(n0 + 128 + ar) * K + (k0 + ccs), &Bs[buf][128 + ar][cc]);
  };
  auto compute = [&](int buf) {
    f16x8 af[4], bf[4];
#pragma unroll
    for (int t = 0; t < 4; ++t) {
      af[t] = *reinterpret_cast<const f16x8*>(&As[buf][wm + t * 16 + l16][(l4 ^ rsw) * 8]);
      bf[t] = *reinterpret_cast<const f16x8*>(&Bs[buf][wn + t * 16 + l16][(l4 ^ rsw) * 8]);
    }
#pragma unroll
    for (int i = 0; i < 4; ++i)
#pragma unroll
      for (int j = 0; j < 4; ++j)
        acc[i][j] = __builtin_amdgcn_mfma_f32_16x16x32_f16(af[i], bf[j], acc[i][j], 0, 0, 0);
  };

  stage(0, 0);
  __syncthreads();
  int cur = 0;
  for (int k0 = 0; k0 < K - 32; k0 += 32) {
    stage(cur ^ 1, k0 + 32);   // next tile in flight during compute
    compute(cur);
    __syncthreads();           // drains vmcnt(0): next buffer ready
    cur ^= 1;
  }
  compute(cur);                // last tile, no prefetch

  const int col = l16;      // C/D: col = lane&15, row = (lane>>4)*4 + reg
  const int r0  = l4 * 4;
#pragma unroll
  for (int i = 0; i < 4; ++i)
#pragma unroll
    for (int j = 0; j < 4; ++j) {
      const int gn = n0 + wn + j * 16 + col;
#pragma unroll
      for (int r = 0; r < 4; ++r) {
        const int gm = m0 + wm + i * 16 + r0 + r;
        C[(size_t)gm * N + gn] = (_Float16)acc[i][j][r];
      }
    }
}

// ---------------------------------------------------------------------------
// K3: scan pass 1. 2 heads per 256-thr block; all-f32 LDS; 2-d-per-lane.
// Unchanged from R8 (measured improvement).
// ---------------------------------------------------------------------------
__global__ __launch_bounds__(256) void scan_pass1(
    const _Float16* __restrict__ proj16, const float* __restrict__ dtb,
    const float* __restrict__ negA, const float* __restrict__ conv_w,
    const float* __restrict__ conv_b, float* __restrict__ H,
    float* __restrict__ sdt) {
  __shared__ alignas(16) float Ad[2][kQH][64];   // 8 KB
  __shared__ alignas(16) float Bd[2][kQH][64];   // 8 KB
  __shared__ alignas(16) float Xd[2][kQH][64];   // 8 KB (xdt f32)
  __shared__ float dts[2][kQ];
  const int tid  = threadIdx.x;
  const int g    = blockIdx.x;
  const int c    = g & (kNC - 1);
  const int bnp  = g >> 5;
  const int lane = tid & 63;
  const int w    = tid >> 6;
  const int hb   = w >> 1;
  const int wd   = w & 1;
  const int sg   = lane >> 4;
  const int dd   = lane & 15;
  const int bn   = bnp * 2 + hb;
  const int b    = bn >> 5, n = bn & 31;
  const int l0   = c * kQ;
  const int d0   = wd * 32 + dd * 2;
  const int t128 = tid & 127;
  const int shb  = tid >> 7;   // staging: which head this thread serves

  f4 hA[4] = {}, hB[4] = {};

  for (int p = 0; p < 2; ++p) {
    const int r0 = p * kQH;
    // ---- stage (128 thr per head): row = t128>>3, 8-ch slice ----
    {
      const int sn  = (bnp * 2 + shb) & 31;
      const int sb  = (bnp * 2 + shb) >> 5;
      const int row = t128 >> 3;
      const int ch  = (t128 & 7) * 8;
      const int gl  = l0 + r0 + row;
      const float dtl = dtb[(size_t)(bnp * 2 + shb) * kL + gl];
      if ((t128 & 7) == 0) dts[shb][r0 + row] = dtl;
      // B: f16 -> f32
      const f16x8 vb = *(const f16x8*)(proj16 +
          (size_t)(sb * kL + gl) * kPROJW + 4096 + sn * 64 + ch);
      f4 blo, bhi;
      blo[0]=(float)vb[0]; blo[1]=(float)vb[1]; blo[2]=(float)vb[2]; blo[3]=(float)vb[3];
      bhi[0]=(float)vb[4]; bhi[1]=(float)vb[5]; bhi[2]=(float)vb[6]; bhi[3]=(float)vb[7];
      *(f4*)&Bd[shb][row][ch]     = blo;
      *(f4*)&Bd[shb][row][ch + 4] = bhi;
      // A: exp
#pragma unroll
      for (int j = 0; j < 8; ++j)
        Ad[shb][row][ch + j] = __expf(negA[sn * 64 + ch + j] * dtl);
      // conv + silu -> xdt (f32)
      float acc[8];
#pragma unroll
      for (int j = 0; j < 8; ++j) acc[j] = conv_b[sn * 64 + ch + j];
#pragma unroll
      for (int jj = 0; jj < 4; ++jj) {
        const int r = gl - 3 + jj;
        if (r < 0) continue;
        const f16x8 v0 = *(const f16x8*)(proj16 + (size_t)(sb * kL + r) * kPROJW + sn * 64 + ch);
#pragma unroll
        for (int j = 0; j < 8; ++j)
          acc[j] += conv_w[(sn * 64 + ch + j) * 4 + jj] * (float)v0[j];
      }
#pragma unroll
      for (int j = 0; j < 8; ++j)
        Xd[shb][row][ch + j] = dtl * (acc[j] * sigm(acc[j]));
    }
    __syncthreads();

    // ---- compute ----
#pragma unroll 2
    for (int tt = 0; tt < kQH; ++tt) {
      const f2 xv = *(const f2*)&Xd[hb][tt][d0];
      const float x0 = xv[0], x1 = xv[1];
#pragma unroll
      for (int q = 0; q < 4; ++q) {
        const f4 a  = ((const f4*)&Ad[hb][tt][sg * 16])[q];
        const f4 bb = ((const f4*)&Bd[hb][tt][sg * 16])[q];
        hA[q] = a * hA[q] + bb * x0;
        hB[q] = a * hB[q] + bb * x1;
      }
    }
    __syncthreads();
  }

  if (t128 == 0) {     // tid 0 -> head 0, tid 128 -> head 1
    float s = 0.f;
    for (int t = 0; t < kQ; ++t) s += dts[shb][t];
    sdt[(bnp * 2 + shb) * kNC + c] = s;
  }

  float* hp = H + (((size_t)bn * kNC + c) * 64 + sg * 16) * 64 + d0;
#pragma unroll
  for (int q = 0; q < 4; ++q)
#pragma unroll
    for (int i = 0; i < 4; ++i) {
      f2 hv; hv[0] = hA[q][i]; hv[1] = hB[q][i];
      *(f2*)&hp[(size_t)(q * 4 + i) * 64] = hv;
    }
}

// ---------------------------------------------------------------------------
// K4: chunk stitching IN-PLACE: H[c] holds local sums on entry, carry-in
// h_in[c] on exit. h_in[c+1] = exp(negA_s*sdt[c])*h_in[c] + hloc[c].
// ---------------------------------------------------------------------------
__global__ __launch_bounds__(256) void scan_pass2(
    float* __restrict__ H, const float* __restrict__ sdt,
    const float* __restrict__ negA) {
  const int bn = blockIdx.x >> 2;
  const int dq = blockIdx.x & 3;
  const int n  = bn & 31;
  const int s  = threadIdx.x >> 2;
  const int d0 = dq * 16 + (threadIdx.x & 3) * 4;
  const float Aa = negA[n * 64 + s];
  f4 h = {};
  for (int c = 0; c < kNC; ++c) {
    const size_t off = (((size_t)bn * kNC + c) * 64 + s) * 64 + d0;
    const float ap = __expf(Aa * sdt[bn * kNC + c]);
    const f4 hl = *(const f4*)(H + off);   // local sums
    *(f4*)(H + off) = h;                   // overwrite with carry-in
    h = ap * h + hl;
  }
}

// ---------------------------------------------------------------------------
// K5: scan pass 3. 2-head packing, all-f32 A/B/C/X LDS. Unchanged from R8.
// ---------------------------------------------------------------------------
__global__ __launch_bounds__(256) void scan_pass3(
    const _Float16* __restrict__ proj16, const float* __restrict__ dtb,
    const float* __restrict__ negA, const float* __restrict__ conv_w,
    const float* __restrict__ conv_b, const float* __restrict__ H,
    const float* __restrict__ Dv, _Float16* __restrict__ yin) {
  __shared__ alignas(16) float Ad[2][kQH][64];     // 8 KB
  __shared__ alignas(16) float Bd[2][kQH][64];     // 8 KB
  __shared__ alignas(16) float Cd[2][kQH][64];     // 8 KB
  __shared__ alignas(16) float Xd[2][kQH][64];     // 8 KB (xdt f32)
  __shared__ alignas(16) _Float16 Xs[2][kQH][64];  // 2 KB (xsilu f16)
  __shared__ alignas(16) _Float16 Zd[2][kQH][64];  // 2 KB (raw z)
  const int tid  = threadIdx.x;
  const int g    = blockIdx.x;
  const int c    = g & (kNC - 1);
  const int bnp  = g >> 5;
  const int lane = tid & 63;
  const int w    = tid >> 6;
  const int hb   = w >> 1;
  const int wd   = w & 1;
  const int sg   = lane >> 4;
  const int dd   = lane & 15;
  const int bn   = bnp * 2 + hb;
  const int b    = bn >> 5, n = bn & 31;
  const int l0   = c * kQ;
  const int d0   = wd * 32 + dd * 2;
  const int t128 = tid & 127;
  const int shb  = tid >> 7;

  // h init from carry-in (registers, carried across both phases)
  f4 hA[4], hB[4];
  {
    const float* hp = H + (((size_t)bn * kNC + c) * 64 + sg * 16) * 64 + d0;
#pragma unroll
    for (int q = 0; q < 4; ++q)
#pragma unroll
      for (int i = 0; i < 4; ++i) {
        const f2 hv = *(const f2*)&hp[(size_t)(q * 4 + i) * 64];
        hA[q][i] = hv[0]; hB[q][i] = hv[1];
      }
  }
  const float Dn = Dv[n];
  _Float16* Yb = yin + (size_t)(b * kL + l0) * kDI + n * 64 + d0;

  for (int p = 0; p < 2; ++p) {
    const int r0 = p * kQH;
    // ---- stage (128 thr per head) ----
    {
      const int sn  = (bnp * 2 + shb) & 31;
      const int sb  = (bnp * 2 + shb) >> 5;
      const int row = t128 >> 3;
      const int ch  = (t128 & 7) * 8;
      const int gl  = l0 + r0 + row;
      const _Float16* base = proj16 + (size_t)(sb * kL + gl) * kPROJW + sn * 64 + ch;
      async_ld16(base + 2048, &Zd[shb][row][ch]);
      const float dtl = dtb[(size_t)(bnp * 2 + shb) * kL + gl];
      // B, C: f16 -> f32
      const f16x8 vb = *(const f16x8*)(base + 4096);
      const f16x8 vc = *(const f16x8*)(base + 6144);
      f4 blo, bhi, clo, chi;
      blo[0]=(float)vb[0]; blo[1]=(float)vb[1]; blo[2]=(float)vb[2]; blo[3]=(float)vb[3];
      bhi[0]=(float)vb[4]; bhi[1]=(float)vb[5]; bhi[2]=(float)vb[6]; bhi[3]=(float)vb[7];
      clo[0]=(float)vc[0]; clo[1]=(float)vc[1]; clo[2]=(float)vc[2]; clo[3]=(float)vc[3];
      chi[0]=(float)vc[4]; chi[1]=(float)vc[5]; chi[2]=(float)vc[6]; chi[3]=(float)vc[7];
      *(f4*)&Bd[shb][row][ch]     = blo;
      *(f4*)&Bd[shb][row][ch + 4] = bhi;
      *(f4*)&Cd[shb][row][ch]     = clo;
      *(f4*)&Cd[shb][row][ch + 4] = chi;
      // A: exp
#pragma unroll
      for (int j = 0; j < 8; ++j)
        Ad[shb][row][ch + j] = __expf(negA[sn * 64 + ch + j] * dtl);
      // conv + silu -> xsilu (f16) and xdt (f32)
      float acc[8];
#pragma unroll
      for (int j = 0; j < 8; ++j) acc[j] = conv_b[sn * 64 + ch + j];
#pragma unroll
      for (int jj = 0; jj < 4; ++jj) {
        const int r = gl - 3 + jj;
        if (r < 0) continue;
        const f16x8 v0 = *(const f16x8*)(proj16 + (size_t)(sb * kL + r) * kPROJW + sn * 64 + ch);
#pragma unroll
        for (int j = 0; j < 8; ++j)
          acc[j] += conv_w[(sn * 64 + ch + j) * 4 + jj] * (float)v0[j];
      }
      f16x8 xo;
#pragma unroll
      for (int j = 0; j < 8; ++j) {
        const float xs = acc[j] * sigm(acc[j]);
        xo[j] = (_Float16)xs;
        Xd[shb][row][ch + j] = dtl * xs;
      }
      *(f16x8*)&Xs[shb][row][ch] = xo;
    }
    __syncthreads();

    // ---- compute ----
#pragma unroll 2
    for (int tt = 0; tt < kQH; ++tt) {
      const f2 xv = *(const f2*)&Xd[hb][tt][d0];
      const float x0 = xv[0], x1 = xv[1];
      f4 pvA = {}, pvB = {};
#pragma unroll
      for (int q = 0; q < 4; ++q) {
        const f4 a  = ((const f4*)&Ad[hb][tt][sg * 16])[q];
        const f4 bb = ((const f4*)&Bd[hb][tt][sg * 16])[q];
        const f4 cc = ((const f4*)&Cd[hb][tt][sg * 16])[q];
        hA[q] = a * hA[q] + bb * x0;
        hB[q] = a * hB[q] + bb * x1;
        pvA = pvA + cc * hA[q];
        pvB = pvB + cc * hB[q];
      }
      float pA = (pvA[0] + pvA[1]) + (pvA[2] + pvA[3]);
      float pB = (pvB[0] + pvB[1]) + (pvB[2] + pvB[3]);
      pA += __shfl_xor(pA, 16);
      pA += __shfl_xor(pA, 32);
      pB += __shfl_xor(pB, 16);
      pB += __shfl_xor(pB, 32);
      if (sg == 0) {
        const f16x2 zv = *(const f16x2*)&Zd[hb][tt][d0];
        const f16x2 xs = *(const f16x2*)&Xs[hb][tt][d0];
        const float z0 = (float)zv[0], z1 = (float)zv[1];
        const float y0 = (pA + Dn * (float)xs[0]) * (z0 * sigm(z0));
        const float y1 = (pB + Dn * (float)xs[1]) * (z1 * sigm(z1));
        f16x2 yv; yv[0] = (_Float16)y0; yv[1] = (_Float16)y1;
        *(f16x2*)&Yb[(size_t)(r0 + tt) * kDI] = yv;
      }
    }
    __syncthreads();
  }
}

// ---------------------------------------------------------------------------
// K6: out[2048,1024] f32 = yin @ Wo16^T. 64x64 tile, BK=32, dbuf prefetch,
// XCD swizzle (nwg=512), XOR-swizzle. Unchanged from R9.
// ---------------------------------------------------------------------------
__global__ __launch_bounds__(256) void gemm_out(
    const _Float16* __restrict__ A, const _Float16* __restrict__ Bm,
    float* __restrict__ C) {
  __shared__ alignas(16) _Float16 As[2][64][32];
  __shared__ alignas(16) _Float16 Bs[2][64][32];
  const int tid  = threadIdx.x;
  const int lane = tid & 63;
  const int w    = tid >> 6;
  const int id   = blockIdx.x;
  const int sw   = (id & 7) * 64 + (id >> 3);    // XCD swizzle (nwg=512)
  const int m0   = (sw >> 4) * 64;               // 32 M-tiles
  const int n0   = (sw & 15) * 64;               // 16 N-tiles
  const int row  = tid >> 2;
  const int cc   = (tid & 3) * 8;                          // linear LDS chunk
  const int ccs  = (((lane & 3) ^ ((lane >> 3) & 3))) * 8; // swizzled global chunk
  const int wm   = (w & 1) * 32;
  const int wn   = (w >> 1) * 32;
  const int l16  = lane & 15;
  const int l4   = lane >> 4;
  const int rsw  = (l16 >> 1) & 3;                         // read-side XOR

  f4 acc[2][2] = {};

  auto stage = [&](int buf, int k0) {
    async_ld16(A + (size_t)(m0 + row) * kDI + (k0 + ccs), &As[buf][row][cc]);
    async_ld16(Bm + (size_t)(n0 + row) * kDI + (k0 + ccs), &Bs[buf][row][cc]);
  };
  auto compute = [&](int buf) {
    f16x8 af[2], bf[2];
#pragma unroll
    for (int t = 0; t < 2; ++t) {
      af[t] = *reinterpret_cast<const f16x8*>(&As[buf][wm + t * 16 + l16][(l4 ^ rsw) * 8]);
      bf[t] = *reinterpret_cast<const f16x8*>(&Bs[buf][wn + t * 16 + l16][(l4 ^ rsw) * 8]);
    }
#pragma unroll
    for (int i = 0; i < 2; ++i)
#pragma unroll
      for (int j = 0; j < 2; ++j)
        acc[i][j] = __builtin_amdgcn_mfma_f32_16x16x32_f16(af[i], bf[j], acc[i][j], 0, 0, 0);
  };

  stage(0, 0);
  __syncthreads();
  int cur = 0;
  for (int k0 = 0; k0 < kDI - 32; k0 += 32) {
    stage(cur ^ 1, k0 + 32);
    compute(cur);
    __syncthreads();
    cur ^= 1;
  }
  compute(cur);

  const int col = l16;
  const int r0  = l4 * 4;
#pragma unroll
  for (int i = 0; i < 2; ++i)
#pragma unroll
    for (int j = 0; j < 2; ++j) {
      const int gn = n0 + wn + j * 16 + col;
#pragma unroll
      for (int r = 0; r < 4; ++r) {
        const int gm = m0 + wm + i * 16 + r0 + r;
        C[(size_t)gm * kDM + gn] = acc[i][j][r];
      }
    }
}

// ---------------------------------------------------------------------------
extern "C" void kernel_launch(void* const* d_in, const int* in_sizes, int n_in,
                              void* d_out, int out_size, void* d_ws, size_t ws_size,
                              hipStream_t stream) {
  const float* x      = (const float*)d_in[0];
  const float* W_in   = (const float*)d_in[1];
  const float* conv_w = (const float*)d_in[2];
  const float* conv_b = (const float*)d_in[3];
  const float* A_log  = (const float*)d_in[4];
  const float* Dv     = (const float*)d_in[5];
  const float* dt_b   = (const float*)d_in[6];
  const float* W_out  = (const float*)d_in[7];
  float* out = (float*)d_out;

  char* p = (char*)d_ws;
  _Float16* proj16 = (_Float16*)p; p += (size_t)kBL * kPROJW * 2;   // 33.6 MB
  float* dtb   = (float*)p; p += (size_t)64 * kL * 4;
  float* negA  = (float*)p; p += 2048 * 4;
  float* WdtT  = (float*)p; p += (size_t)1024 * 32 * 4;             // 128 KB
  float* sdt   = (float*)p; p += (size_t)64 * kNC * 4 + 3968;       // 8 KB + pad
  float* H     = (float*)p; p += (size_t)64 * kNC * 64 * 64 * 4;    // 33.6 MB (local sums -> carry-ins, in place)
  _Float16* yin  = (_Float16*)p; p += (size_t)kBL * kDI * 2;        // 8.4 MB
  _Float16* Wo16 = (_Float16*)p; p += (size_t)kDM * kDI * 2;        // 4.2 MB
  _Float16* x16  = (_Float16*)H;                    // alias (pre-scan phase)
  _Float16* Wi16 = x16 + (size_t)kBL * kDM;         // 16.8 MB, fits in H (33.6)

  prep_inputs<<<kCvtBlocks + kNegABlocks, 256, 0, stream>>>(
      x, W_in, W_out, A_log, x16, Wi16, Wo16, WdtT, negA);

  dt_gemm<<<kBL / 4, 256, 0, stream>>>(x, WdtT, dt_b, dtb);

  gemm1<<<(kBL / 128) * (kPROJW / 256), 512, 0, stream>>>(
      x16, Wi16, proj16, kBL, kPROJW, kDM);

  scan_pass1<<<(64 / 2) * kNC, 256, 0, stream>>>(proj16, dtb, negA, conv_w, conv_b, H, sdt);
  scan_pass2<<<256, 256, 0, stream>>>(H, sdt, negA);
  scan_pass3<<<(64 / 2) * kNC, 256, 0, stream>>>(proj16, dtb, negA, conv_w, conv_b, H, Dv, yin);

  gemm_out<<<(kBL / 64) * (kDM / 64), 256, 0, stream>>>(yin, Wo16, out);
}

// Round 11
// 283.023 us; speedup vs baseline: 1.0811x; 1.0389x over previous
//
#include <hip/hip_runtime.h>
#include <hip/hip_fp16.h>

namespace {
constexpr int kB  = 2;
constexpr int kL  = 1024;
constexpr int kDM = 1024;
constexpr int kDI = 2048;
constexpr int kPROJW = 8192;   // proj16 row: [x 0..2048 | z ..4096 | B ..6144 | C ..8192]
constexpr int kBL = 2048;
constexpr int kQ  = 32;        // chunk length
constexpr int kQH = 16;        // rows staged per phase
constexpr int kNC = 32;        // chunks per (b,n)
constexpr int kCvtX = kBL * kDM / 4;      // 524288 vec4
constexpr int kCvtW = 8224 * kDM / 4;     // 2105344 (8192 cvt rows + 32 dt rows -> WdtT)
constexpr int kCvtO = kDM * kDI / 4;      // 524288
constexpr int kCvtBlocks  = (kCvtX + kCvtW + kCvtO) / 256;  // 12320
constexpr int kNegABlocks = 8;
}

typedef float f4 __attribute__((ext_vector_type(4)));
typedef float f2 __attribute__((ext_vector_type(2)));
typedef _Float16 f16x8 __attribute__((ext_vector_type(8)));
typedef _Float16 f16x4 __attribute__((ext_vector_type(4)));
typedef _Float16 f16x2 __attribute__((ext_vector_type(2)));

__device__ __forceinline__ void async_ld16(const void* g, void* l) {
  __builtin_amdgcn_global_load_lds(
      (const __attribute__((address_space(1))) void*)g,
      (__attribute__((address_space(3))) void*)l, 16, 0, 0);
}

__device__ __forceinline__ float sigm(float v) {
  return __builtin_amdgcn_rcpf(1.f + __expf(-v));   // 1-instr rcp vs IEEE div
}

// ---------------------------------------------------------------------------
// K1: f32->f16 cvt of x / W_in(row-permuted) / W_out + WdtT pack + negA.
// ---------------------------------------------------------------------------
__global__ __launch_bounds__(256) void prep_inputs(
    const float* __restrict__ x, const float* __restrict__ W_in,
    const float* __restrict__ W_out, const float* __restrict__ A_log,
    _Float16* __restrict__ x16, _Float16* __restrict__ Wi16,
    _Float16* __restrict__ Wo16, float* __restrict__ WdtT,
    float* __restrict__ negA) {
  const int bid = blockIdx.x;
  const int tid = threadIdx.x;
  if (bid < kCvtBlocks) {
    int i = bid * 256 + tid;
    if (i < kCvtX) {
      const f4 v = ((const f4*)x)[i];
      f16x4 o; o[0]=(_Float16)v[0]; o[1]=(_Float16)v[1]; o[2]=(_Float16)v[2]; o[3]=(_Float16)v[3];
      ((f16x4*)x16)[i] = o;
    } else if (i < kCvtX + kCvtW) {
      i -= kCvtX;
      const int row = i >> 8;        // [0, 8224)
      const int cv  = i & 255;
      if (row < 8192) {
        int srow;
        if (row < 4096)      srow = row;
        else if (row < 6144) { const int m = row - 4096; srow = 4096 + (m >> 6) * 129 + (m & 63); }
        else                 { const int m = row - 6144; srow = 4096 + (m >> 6) * 129 + 64 + (m & 63); }
        const f4 v = ((const f4*)(W_in + (size_t)srow * kDM))[cv];
        f16x4 o; o[0]=(_Float16)v[0]; o[1]=(_Float16)v[1]; o[2]=(_Float16)v[2]; o[3]=(_Float16)v[3];
        ((f16x4*)(Wi16 + (size_t)row * kDM))[cv] = o;
      } else {
        const int h = row - 8192;    // dt row -> transposed f32 pack
        const f4 v = ((const f4*)(W_in + (size_t)(4096 + h * 129 + 128) * kDM))[cv];
        const int k = cv * 4;
        WdtT[(k + 0) * 32 + h] = v[0];
        WdtT[(k + 1) * 32 + h] = v[1];
        WdtT[(k + 2) * 32 + h] = v[2];
        WdtT[(k + 3) * 32 + h] = v[3];
      }
    } else {
      i -= kCvtX + kCvtW;
      const f4 v = ((const f4*)W_out)[i];
      f16x4 o; o[0]=(_Float16)v[0]; o[1]=(_Float16)v[1]; o[2]=(_Float16)v[2]; o[3]=(_Float16)v[3];
      ((f16x4*)Wo16)[i] = o;
    }
  } else {
    const int i = (bid - kCvtBlocks) * 256 + tid;
    if (i < 2048) negA[i] = -__expf(A_log[i]);
  }
}

// ---------------------------------------------------------------------------
// K1b: dtb = softplus(x @ Wdt^T + bias), f32 exact.
// ---------------------------------------------------------------------------
__global__ __launch_bounds__(256) void dt_gemm(
    const float* __restrict__ x, const float* __restrict__ WdtT,
    const float* __restrict__ dt_bias, float* __restrict__ dtb) {
  __shared__ alignas(16) float Xs[4][1024];   // 16 KB
  __shared__ float Ps[4][8][32];              // 4 KB
  const int tid = threadIdx.x;
  const int gm0 = blockIdx.x * 4;
#pragma unroll
  for (int q = 0; q < 4; ++q)
    *(f4*)&Xs[q][tid * 4 - (tid >> 8)] = *(const f4*)(x + (size_t)(gm0 + q) * kDM + tid * 4);
  __syncthreads();

  const int h  = tid & 31;
  const int sl = tid >> 5;
  const int k0 = sl * 128;
  float p0 = 0.f, p1 = 0.f, p2 = 0.f, p3 = 0.f;
#pragma unroll 8
  for (int i = 0; i < 128; ++i) {
    const float w = WdtT[(k0 + i) * 32 + h];
    p0 = fmaf(Xs[0][k0 + i], w, p0);
    p1 = fmaf(Xs[1][k0 + i], w, p1);
    p2 = fmaf(Xs[2][k0 + i], w, p2);
    p3 = fmaf(Xs[3][k0 + i], w, p3);
  }
  Ps[0][sl][h] = p0; Ps[1][sl][h] = p1; Ps[2][sl][h] = p2; Ps[3][sl][h] = p3;
  __syncthreads();
  if (tid < 128) {
    const int r = tid >> 5, hh = tid & 31;
    float v = 0.f;
#pragma unroll
    for (int s2 = 0; s2 < 8; ++s2) v += Ps[r][s2][hh];
    const float dtp = v + dt_bias[hh];
    const float dt  = (dtp > 20.f) ? dtp : log1pf(__expf(dtp));
    const int gm = gm0 + r;
    dtb[(size_t)((gm >> 10) * 32 + hh) * kL + (gm & 1023)] = dt;
  }
}

// ---------------------------------------------------------------------------
// K2: f16 GEMM, BM=128 x BN=256 tile, 512 thr (8 waves), BK=32, dbuf
// prefetch, T2 XOR-swizzle, XCD swizzle. Unchanged from R10 (measured win).
// ---------------------------------------------------------------------------
__global__ __launch_bounds__(512) void gemm1(
    const _Float16* __restrict__ A, const _Float16* __restrict__ Bm,
    _Float16* __restrict__ C, int M, int N, int K) {
  __shared__ alignas(16) _Float16 As[2][128][32];
  __shared__ alignas(16) _Float16 Bs[2][256][32];
  const int tid  = threadIdx.x;      // 0..511
  const int lane = tid & 63;
  const int w    = tid >> 6;         // 0..7
  const int id   = blockIdx.x;
  const int sw   = (id & 7) * 64 + (id >> 3);    // XCD swizzle (nwg=512)
  const int m0   = (sw & 15) * 128;              // 16 M tiles
  const int n0   = (sw >> 4) * 256;              // 32 N tiles
  const int ar   = tid >> 2;                     // staging row 0..127
  const int cc   = (tid & 3) * 8;                            // linear LDS chunk
  const int ccs  = (((tid & 3) ^ ((tid >> 3) & 3))) * 8;     // swizzled global chunk
  const int wm   = (w & 1) * 64;                 // wave M offset (2 x 64)
  const int wn   = (w >> 1) * 64;                // wave N offset (4 x 64)
  const int l16  = lane & 15;
  const int l4   = lane >> 4;
  const int rsw  = (l16 >> 1) & 3;               // read-side XOR key

  f4 acc[4][4] = {};

  auto stage = [&](int buf, int k0) {
    async_ld16(A  + (size_t)(m0 + ar) * K + (k0 + ccs), &As[buf][ar][cc]);
    async_ld16(Bm + (size_t)(n0 + ar) * K + (k0 + ccs), &Bs[buf][ar][cc]);
    async_ld16(Bm + (size_t)(n0 + 128 + ar) * K + (k0 + ccs), &Bs[buf][128 + ar][cc]);
  };
  auto compute = [&](int buf) {
    f16x8 af[4], bf[4];
#pragma unroll
    for (int t = 0; t < 4; ++t) {
      af[t] = *reinterpret_cast<const f16x8*>(&As[buf][wm + t * 16 + l16][(l4 ^ rsw) * 8]);
      bf[t] = *reinterpret_cast<const f16x8*>(&Bs[buf][wn + t * 16 + l16][(l4 ^ rsw) * 8]);
    }
#pragma unroll
    for (int i = 0; i < 4; ++i)
#pragma unroll
      for (int j = 0; j < 4; ++j)
        acc[i][j] = __builtin_amdgcn_mfma_f32_16x16x32_f16(af[i], bf[j], acc[i][j], 0, 0, 0);
  };

  stage(0, 0);
  __syncthreads();
  int cur = 0;
  for (int k0 = 0; k0 < K - 32; k0 += 32) {
    stage(cur ^ 1, k0 + 32);   // next tile in flight during compute
    compute(cur);
    __syncthreads();           // drains vmcnt(0): next buffer ready
    cur ^= 1;
  }
  compute(cur);                // last tile, no prefetch

  const int col = l16;      // C/D: col = lane&15, row = (lane>>4)*4 + reg
  const int r0  = l4 * 4;
#pragma unroll
  for (int i = 0; i < 4; ++i)
#pragma unroll
    for (int j = 0; j < 4; ++j) {
      const int gn = n0 + wn + j * 16 + col;
#pragma unroll
      for (int r = 0; r < 4; ++r) {
        const int gm = m0 + wm + i * 16 + r0 + r;
        C[(size_t)gm * N + gn] = (_Float16)acc[i][j][r];
      }
    }
}

// ---------------------------------------------------------------------------
// K3: scan pass 1. 2 heads per 256-thr block. NEW lane map: g=lane>>3 owns
// s in [8g,8g+8), dd=lane&7 owns d0=wd*32+dd*4 (4 d). A/B f4 reads now have
// 8 distinct 16B chunks per instr (full 128B LDS width) -> 5 DS instr per
// wave-t vs 9. h = f4[8] (32 VGPR, same as before). Staging unchanged.
// ---------------------------------------------------------------------------
__global__ __launch_bounds__(256) void scan_pass1(
    const _Float16* __restrict__ proj16, const float* __restrict__ dtb,
    const float* __restrict__ negA, const float* __restrict__ conv_w,
    const float* __restrict__ conv_b, float* __restrict__ H,
    float* __restrict__ sdt) {
  __shared__ alignas(16) float Ad[2][kQH][64];   // 8 KB
  __shared__ alignas(16) float Bd[2][kQH][64];   // 8 KB
  __shared__ alignas(16) float Xd[2][kQH][64];   // 8 KB (xdt f32)
  __shared__ float dts[2][kQ];
  const int tid  = threadIdx.x;
  const int g    = blockIdx.x;
  const int c    = g & (kNC - 1);
  const int bnp  = g >> 5;
  const int lane = tid & 63;
  const int w    = tid >> 6;
  const int hb   = w >> 1;
  const int wd   = w & 1;
  const int sg8  = lane >> 3;      // s-group (8 s each)
  const int dd   = lane & 7;
  const int bn   = bnp * 2 + hb;
  const int l0   = c * kQ;
  const int d0   = wd * 32 + dd * 4;
  const int t128 = tid & 127;
  const int shb  = tid >> 7;   // staging: which head this thread serves

  f4 h[8] = {};

  for (int p = 0; p < 2; ++p) {
    const int r0 = p * kQH;
    // ---- stage (128 thr per head): row = t128>>3, 8-ch slice ----
    {
      const int sn  = (bnp * 2 + shb) & 31;
      const int sb  = (bnp * 2 + shb) >> 5;
      const int row = t128 >> 3;
      const int ch  = (t128 & 7) * 8;
      const int gl  = l0 + r0 + row;
      const float dtl = dtb[(size_t)(bnp * 2 + shb) * kL + gl];
      if ((t128 & 7) == 0) dts[shb][r0 + row] = dtl;
      // B: f16 -> f32
      const f16x8 vb = *(const f16x8*)(proj16 +
          (size_t)(sb * kL + gl) * kPROJW + 4096 + sn * 64 + ch);
      f4 blo, bhi;
      blo[0]=(float)vb[0]; blo[1]=(float)vb[1]; blo[2]=(float)vb[2]; blo[3]=(float)vb[3];
      bhi[0]=(float)vb[4]; bhi[1]=(float)vb[5]; bhi[2]=(float)vb[6]; bhi[3]=(float)vb[7];
      *(f4*)&Bd[shb][row][ch]     = blo;
      *(f4*)&Bd[shb][row][ch + 4] = bhi;
      // A: exp
#pragma unroll
      for (int j = 0; j < 8; ++j)
        Ad[shb][row][ch + j] = __expf(negA[sn * 64 + ch + j] * dtl);
      // conv + silu -> xdt (f32)
      float acc[8];
#pragma unroll
      for (int j = 0; j < 8; ++j) acc[j] = conv_b[sn * 64 + ch + j];
#pragma unroll
      for (int jj = 0; jj < 4; ++jj) {
        const int r = gl - 3 + jj;
        if (r < 0) continue;
        const f16x8 v0 = *(const f16x8*)(proj16 + (size_t)(sb * kL + r) * kPROJW + sn * 64 + ch);
#pragma unroll
        for (int j = 0; j < 8; ++j)
          acc[j] += conv_w[(sn * 64 + ch + j) * 4 + jj] * (float)v0[j];
      }
#pragma unroll
      for (int j = 0; j < 8; ++j)
        Xd[shb][row][ch + j] = dtl * (acc[j] * sigm(acc[j]));
    }
    __syncthreads();

    // ---- compute ----
#pragma unroll 2
    for (int tt = 0; tt < kQH; ++tt) {
      const f4 xv = *(const f4*)&Xd[hb][tt][d0];
      const f4 a0 = ((const f4*)&Ad[hb][tt][sg8 * 8])[0];
      const f4 a1 = ((const f4*)&Ad[hb][tt][sg8 * 8])[1];
      const f4 b0 = ((const f4*)&Bd[hb][tt][sg8 * 8])[0];
      const f4 b1 = ((const f4*)&Bd[hb][tt][sg8 * 8])[1];
#pragma unroll
      for (int si = 0; si < 4; ++si) {
        h[si]     = a0[si] * h[si]     + b0[si] * xv;
        h[si + 4] = a1[si] * h[si + 4] + b1[si] * xv;
      }
    }
    __syncthreads();
  }

  if (t128 == 0) {     // tid 0 -> head 0, tid 128 -> head 1
    float s = 0.f;
    for (int t = 0; t < kQ; ++t) s += dts[shb][t];
    sdt[(bnp * 2 + shb) * kNC + c] = s;
  }

  float* hp = H + (((size_t)bn * kNC + c) * 64 + sg8 * 8) * 64 + d0;
#pragma unroll
  for (int si = 0; si < 8; ++si)
    *(f4*)&hp[(size_t)si * 64] = h[si];
}

// ---------------------------------------------------------------------------
// K4: chunk stitching IN-PLACE, scalar-d regrid: 1024 blocks x 256 thr,
// thread = (s = sq*4 + tid>>6, d = tid&63); 256B coalesced rows, 4x TLP.
// ---------------------------------------------------------------------------
__global__ __launch_bounds__(256) void scan_pass2(
    float* __restrict__ H, const float* __restrict__ sdt,
    const float* __restrict__ negA) {
  const int bn = blockIdx.x >> 4;       // 64
  const int sq = blockIdx.x & 15;       // 16
  const int s  = sq * 4 + (threadIdx.x >> 6);
  const int d  = threadIdx.x & 63;
  const int n  = bn & 31;
  const float Aa = negA[n * 64 + s];
  float h = 0.f;
  for (int c = 0; c < kNC; ++c) {
    const size_t off = (((size_t)bn * kNC + c) * 64 + s) * 64 + d;
    const float ap = __expf(Aa * sdt[bn * kNC + c]);
    const float hl = H[off];   // local sums
    H[off] = h;                // overwrite with carry-in
    h = ap * h + hl;
  }
}

// ---------------------------------------------------------------------------
// K5: scan pass 3. Same 8s x 4d lane map as pass1: 7 DS instr per wave-t
// (A2+B2+C2+X1) vs 13. pv reduce = 3 shfl_xor rounds (g = lane bits 3-5).
// Staging unchanged from R10.
// ---------------------------------------------------------------------------
__global__ __launch_bounds__(256) void scan_pass3(
    const _Float16* __restrict__ proj16, const float* __restrict__ dtb,
    const float* __restrict__ negA, const float* __restrict__ conv_w,
    const float* __restrict__ conv_b, const float* __restrict__ H,
    const float* __restrict__ Dv, _Float16* __restrict__ yin) {
  __shared__ alignas(16) float Ad[2][kQH][64];     // 8 KB
  __shared__ alignas(16) float Bd[2][kQH][64];     // 8 KB
  __shared__ alignas(16) float Cd[2][kQH][64];     // 8 KB
  __shared__ alignas(16) float Xd[2][kQH][64];     // 8 KB (xdt f32)
  __shared__ alignas(16) _Float16 Xs[2][kQH][64];  // 2 KB (xsilu f16)
  __shared__ alignas(16) _Float16 Zd[2][kQH][64];  // 2 KB (raw z)
  const int tid  = threadIdx.x;
  const int g    = blockIdx.x;
  const int c    = g & (kNC - 1);
  const int bnp  = g >> 5;
  const int lane = tid & 63;
  const int w    = tid >> 6;
  const int hb   = w >> 1;
  const int wd   = w & 1;
  const int sg8  = lane >> 3;      // s-group (8 s each)
  const int dd   = lane & 7;
  const int bn   = bnp * 2 + hb;
  const int b    = bn >> 5, n = bn & 31;
  const int l0   = c * kQ;
  const int d0   = wd * 32 + dd * 4;
  const int t128 = tid & 127;
  const int shb  = tid >> 7;

  // h init from carry-in (registers, carried across both phases)
  f4 h[8];
  {
    const float* hp = H + (((size_t)bn * kNC + c) * 64 + sg8 * 8) * 64 + d0;
#pragma unroll
    for (int si = 0; si < 8; ++si)
      h[si] = *(const f4*)&hp[(size_t)si * 64];
  }
  const float Dn = Dv[n];
  _Float16* Yb = yin + (size_t)(b * kL + l0) * kDI + n * 64 + d0;

  for (int p = 0; p < 2; ++p) {
    const int r0 = p * kQH;
    // ---- stage (128 thr per head) ----
    {
      const int sn  = (bnp * 2 + shb) & 31;
      const int sb  = (bnp * 2 + shb) >> 5;
      const int row = t128 >> 3;
      const int ch  = (t128 & 7) * 8;
      const int gl  = l0 + r0 + row;
      const _Float16* base = proj16 + (size_t)(sb * kL + gl) * kPROJW + sn * 64 + ch;
      async_ld16(base + 2048, &Zd[shb][row][ch]);
      const float dtl = dtb[(size_t)(bnp * 2 + shb) * kL + gl];
      // B, C: f16 -> f32
      const f16x8 vb = *(const f16x8*)(base + 4096);
      const f16x8 vc = *(const f16x8*)(base + 6144);
      f4 blo, bhi, clo, chi;
      blo[0]=(float)vb[0]; blo[1]=(float)vb[1]; blo[2]=(float)vb[2]; blo[3]=(float)vb[3];
      bhi[0]=(float)vb[4]; bhi[1]=(float)vb[5]; bhi[2]=(float)vb[6]; bhi[3]=(float)vb[7];
      clo[0]=(float)vc[0]; clo[1]=(float)vc[1]; clo[2]=(float)vc[2]; clo[3]=(float)vc[3];
      chi[0]=(float)vc[4]; chi[1]=(float)vc[5]; chi[2]=(float)vc[6]; chi[3]=(float)vc[7];
      *(f4*)&Bd[shb][row][ch]     = blo;
      *(f4*)&Bd[shb][row][ch + 4] = bhi;
      *(f4*)&Cd[shb][row][ch]     = clo;
      *(f4*)&Cd[shb][row][ch + 4] = chi;
      // A: exp
#pragma unroll
      for (int j = 0; j < 8; ++j)
        Ad[shb][row][ch + j] = __expf(negA[sn * 64 + ch + j] * dtl);
      // conv + silu -> xsilu (f16) and xdt (f32)
      float acc[8];
#pragma unroll
      for (int j = 0; j < 8; ++j) acc[j] = conv_b[sn * 64 + ch + j];
#pragma unroll
      for (int jj = 0; jj < 4; ++jj) {
        const int r = gl - 3 + jj;
        if (r < 0) continue;
        const f16x8 v0 = *(const f16x8*)(proj16 + (size_t)(sb * kL + r) * kPROJW + sn * 64 + ch);
#pragma unroll
        for (int j = 0; j < 8; ++j)
          acc[j] += conv_w[(sn * 64 + ch + j) * 4 + jj] * (float)v0[j];
      }
      f16x8 xo;
#pragma unroll
      for (int j = 0; j < 8; ++j) {
        const float xs = acc[j] * sigm(acc[j]);
        xo[j] = (_Float16)xs;
        Xd[shb][row][ch + j] = dtl * xs;
      }
      *(f16x8*)&Xs[shb][row][ch] = xo;
    }
    __syncthreads();

    // ---- compute ----
#pragma unroll 2
    for (int tt = 0; tt < kQH; ++tt) {
      const f4 xv = *(const f4*)&Xd[hb][tt][d0];
      const f4 a0 = ((const f4*)&Ad[hb][tt][sg8 * 8])[0];
      const f4 a1 = ((const f4*)&Ad[hb][tt][sg8 * 8])[1];
      const f4 b0 = ((const f4*)&Bd[hb][tt][sg8 * 8])[0];
      const f4 b1 = ((const f4*)&Bd[hb][tt][sg8 * 8])[1];
      const f4 c0 = ((const f4*)&Cd[hb][tt][sg8 * 8])[0];
      const f4 c1 = ((const f4*)&Cd[hb][tt][sg8 * 8])[1];
      f4 pv = {};
#pragma unroll
      for (int si = 0; si < 4; ++si) {
        h[si]     = a0[si] * h[si]     + b0[si] * xv;
        pv        = pv + c0[si] * h[si];
        h[si + 4] = a1[si] * h[si + 4] + b1[si] * xv;
        pv        = pv + c1[si] * h[si + 4];
      }
      // reduce over the 8 s-groups (g = lane bits 3..5)
#pragma unroll
      for (int cj = 0; cj < 4; ++cj) {
        float v = pv[cj];
        v += __shfl_xor(v, 8);
        v += __shfl_xor(v, 16);
        v += __shfl_xor(v, 32);
        pv[cj] = v;
      }
      if (sg8 == 0) {
        const f16x4 zv = *(const f16x4*)&Zd[hb][tt][d0];
        const f16x4 xs = *(const f16x4*)&Xs[hb][tt][d0];
        f16x4 yv;
#pragma unroll
        for (int cj = 0; cj < 4; ++cj) {
          const float z = (float)zv[cj];
          yv[cj] = (_Float16)((pv[cj] + Dn * (float)xs[cj]) * (z * sigm(z)));
        }
        *(f16x4*)&Yb[(size_t)(r0 + tt) * kDI] = yv;
      }
    }
    __syncthreads();
  }
}

// ---------------------------------------------------------------------------
// K6: out[2048,1024] f32 = yin @ Wo16^T. 64x64 tile, BK=32, dbuf prefetch,
// XCD swizzle (nwg=512), XOR-swizzle. Unchanged.
// ---------------------------------------------------------------------------
__global__ __launch_bounds__(256) void gemm_out(
    const _Float16* __restrict__ A, const _Float16* __restrict__ Bm,
    float* __restrict__ C) {
  __shared__ alignas(16) _Float16 As[2][64][32];
  __shared__ alignas(16) _Float16 Bs[2][64][32];
  const int tid  = threadIdx.x;
  const int lane = tid & 63;
  const int w    = tid >> 6;
  const int id   = blockIdx.x;
  const int sw   = (id & 7) * 64 + (id >> 3);    // XCD swizzle (nwg=512)
  const int m0   = (sw >> 4) * 64;               // 32 M-tiles
  const int n0   = (sw & 15) * 64;               // 16 N-tiles
  const int row  = tid >> 2;
  const int cc   = (tid & 3) * 8;                          // linear LDS chunk
  const int ccs  = (((lane & 3) ^ ((lane >> 3) & 3))) * 8; // swizzled global chunk
  const int wm   = (w & 1) * 32;
  const int wn   = (w >> 1) * 32;
  const int l16  = lane & 15;
  const int l4   = lane >> 4;
  const int rsw  = (l16 >> 1) & 3;                         // read-side XOR

  f4 acc[2][2] = {};

  auto stage = [&](int buf, int k0) {
    async_ld16(A + (size_t)(m0 + row) * kDI + (k0 + ccs), &As[buf][row][cc]);
    async_ld16(Bm + (size_t)(n0 + row) * kDI + (k0 + ccs), &Bs[buf][row][cc]);
  };
  auto compute = [&](int buf) {
    f16x8 af[2], bf[2];
#pragma unroll
    for (int t = 0; t < 2; ++t) {
      af[t] = *reinterpret_cast<const f16x8*>(&As[buf][wm + t * 16 + l16][(l4 ^ rsw) * 8]);
      bf[t] = *reinterpret_cast<const f16x8*>(&Bs[buf][wn + t * 16 + l16][(l4 ^ rsw) * 8]);
    }
#pragma unroll
    for (int i = 0; i < 2; ++i)
#pragma unroll
      for (int j = 0; j < 2; ++j)
        acc[i][j] = __builtin_amdgcn_mfma_f32_16x16x32_f16(af[i], bf[j], acc[i][j], 0, 0, 0);
  };

  stage(0, 0);
  __syncthreads();
  int cur = 0;
  for (int k0 = 0; k0 < kDI - 32; k0 += 32) {
    stage(cur ^ 1, k0 + 32);
    compute(cur);
    __syncthreads();
    cur ^= 1;
  }
  compute(cur);

  const int col = l16;
  const int r0  = l4 * 4;
#pragma unroll
  for (int i = 0; i < 2; ++i)
#pragma unroll
    for (int j = 0; j < 2; ++j) {
      const int gn = n0 + wn + j * 16 + col;
#pragma unroll
      for (int r = 0; r < 4; ++r) {
        const int gm = m0 + wm + i * 16 + r0 + r;
        C[(size_t)gm * kDM + gn] = acc[i][j][r];
      }
    }
}

// ---------------------------------------------------------------------------
extern "C" void kernel_launch(void* const* d_in, const int* in_sizes, int n_in,
                              void* d_out, int out_size, void* d_ws, size_t ws_size,
                              hipStream_t stream) {
  const float* x      = (const float*)d_in[0];
  const float* W_in   = (const float*)d_in[1];
  const float* conv_w = (const float*)d_in[2];
  const float* conv_b = (const float*)d_in[3];
  const float* A_log  = (const float*)d_in[4];
  const float* Dv     = (const float*)d_in[5];
  const float* dt_b   = (const float*)d_in[6];
  const float* W_out  = (const float*)d_in[7];
  float* out = (float*)d_out;

  char* p = (char*)d_ws;
  _Float16* proj16 = (_Float16*)p; p += (size_t)kBL * kPROJW * 2;   // 33.6 MB
  float* dtb   = (float*)p; p += (size_t)64 * kL * 4;
  float* negA  = (float*)p; p += 2048 * 4;
  float* WdtT  = (float*)p; p += (size_t)1024 * 32 * 4;             // 128 KB
  float* sdt   = (float*)p; p += (size_t)64 * kNC * 4 + 3968;       // 8 KB + pad
  float* H     = (float*)p; p += (size_t)64 * kNC * 64 * 64 * 4;    // 33.6 MB (local sums -> carry-ins, in place)
  _Float16* yin  = (_Float16*)p; p += (size_t)kBL * kDI * 2;        // 8.4 MB
  _Float16* Wo16 = (_Float16*)p; p += (size_t)kDM * kDI * 2;        // 4.2 MB
  _Float16* x16  = (_Float16*)H;                    // alias (pre-scan phase)
  _Float16* Wi16 = x16 + (size_t)kBL * kDM;         // 16.8 MB, fits in H (33.6)

  prep_inputs<<<kCvtBlocks + kNegABlocks, 256, 0, stream>>>(
      x, W_in, W_out, A_log, x16, Wi16, Wo16, WdtT, negA);

  dt_gemm<<<kBL / 4, 256, 0, stream>>>(x, WdtT, dt_b, dtb);

  gemm1<<<(kBL / 128) * (kPROJW / 256), 512, 0, stream>>>(
      x16, Wi16, proj16, kBL, kPROJW, kDM);

  scan_pass1<<<(64 / 2) * kNC, 256, 0, stream>>>(proj16, dtb, negA, conv_w, conv_b, H, sdt);
  scan_pass2<<<64 * 16, 256, 0, stream>>>(H, sdt, negA);
  scan_pass3<<<(64 / 2) * kNC, 256, 0, stream>>>(proj16, dtb, negA, conv_w, conv_b, H, Dv, yin);

  gemm_out<<<(kBL / 64) * (kDM / 64), 256, 0, stream>>>(yin, Wo16, out);
}

// Round 12
// 280.736 us; speedup vs baseline: 1.0899x; 1.0081x over previous
//
#include <hip/hip_runtime.h>
#include <hip/hip_fp16.h>

namespace {
constexpr int kB  = 2;
constexpr int kL  = 1024;
constexpr int kDM = 1024;
constexpr int kDI = 2048;
constexpr int kPROJW = 8192;   // proj16 row: [x 0..2048 | z ..4096 | B ..6144 | C ..8192]
constexpr int kBL = 2048;
constexpr int kQ  = 32;        // chunk length
constexpr int kQH = 16;        // rows staged per phase
constexpr int kNC = 32;        // chunks per (b,n)
constexpr int kCvtX = kBL * kDM / 4;      // 524288 vec4
constexpr int kCvtW = 8224 * kDM / 4;     // 2105344 (8192 cvt rows + 32 dt rows -> WdtT)
constexpr int kCvtO = kDM * kDI / 4;      // 524288
constexpr int kCvtBlocks  = (kCvtX + kCvtW + kCvtO) / 256;  // 12320
constexpr int kNegABlocks = 8;
}

typedef float f4 __attribute__((ext_vector_type(4)));
typedef float f2 __attribute__((ext_vector_type(2)));
typedef _Float16 f16x8 __attribute__((ext_vector_type(8)));
typedef _Float16 f16x4 __attribute__((ext_vector_type(4)));
typedef _Float16 f16x2 __attribute__((ext_vector_type(2)));

__device__ __forceinline__ void async_ld16(const void* g, void* l) {
  __builtin_amdgcn_global_load_lds(
      (const __attribute__((address_space(1))) void*)g,
      (__attribute__((address_space(3))) void*)l, 16, 0, 0);
}

__device__ __forceinline__ float sigm(float v) {
  return __builtin_amdgcn_rcpf(1.f + __expf(-v));   // 1-instr rcp vs IEEE div
}

// ---------------------------------------------------------------------------
// K1: f32->f16 cvt of x / W_in(row-permuted) / W_out + WdtT pack + negA.
// ---------------------------------------------------------------------------
__global__ __launch_bounds__(256) void prep_inputs(
    const float* __restrict__ x, const float* __restrict__ W_in,
    const float* __restrict__ W_out, const float* __restrict__ A_log,
    _Float16* __restrict__ x16, _Float16* __restrict__ Wi16,
    _Float16* __restrict__ Wo16, float* __restrict__ WdtT,
    float* __restrict__ negA) {
  const int bid = blockIdx.x;
  const int tid = threadIdx.x;
  if (bid < kCvtBlocks) {
    int i = bid * 256 + tid;
    if (i < kCvtX) {
      const f4 v = ((const f4*)x)[i];
      f16x4 o; o[0]=(_Float16)v[0]; o[1]=(_Float16)v[1]; o[2]=(_Float16)v[2]; o[3]=(_Float16)v[3];
      ((f16x4*)x16)[i] = o;
    } else if (i < kCvtX + kCvtW) {
      i -= kCvtX;
      const int row = i >> 8;        // [0, 8224)
      const int cv  = i & 255;
      if (row < 8192) {
        int srow;
        if (row < 4096)      srow = row;
        else if (row < 6144) { const int m = row - 4096; srow = 4096 + (m >> 6) * 129 + (m & 63); }
        else                 { const int m = row - 6144; srow = 4096 + (m >> 6) * 129 + 64 + (m & 63); }
        const f4 v = ((const f4*)(W_in + (size_t)srow * kDM))[cv];
        f16x4 o; o[0]=(_Float16)v[0]; o[1]=(_Float16)v[1]; o[2]=(_Float16)v[2]; o[3]=(_Float16)v[3];
        ((f16x4*)(Wi16 + (size_t)row * kDM))[cv] = o;
      } else {
        const int h = row - 8192;    // dt row -> transposed f32 pack
        const f4 v = ((const f4*)(W_in + (size_t)(4096 + h * 129 + 128) * kDM))[cv];
        const int k = cv * 4;
        WdtT[(k + 0) * 32 + h] = v[0];
        WdtT[(k + 1) * 32 + h] = v[1];
        WdtT[(k + 2) * 32 + h] = v[2];
        WdtT[(k + 3) * 32 + h] = v[3];
      }
    } else {
      i -= kCvtX + kCvtW;
      const f4 v = ((const f4*)W_out)[i];
      f16x4 o; o[0]=(_Float16)v[0]; o[1]=(_Float16)v[1]; o[2]=(_Float16)v[2]; o[3]=(_Float16)v[3];
      ((f16x4*)Wo16)[i] = o;
    }
  } else {
    const int i = (bid - kCvtBlocks) * 256 + tid;
    if (i < 2048) negA[i] = -__expf(A_log[i]);
  }
}

// ---------------------------------------------------------------------------
// K1b: dtb = softplus(x @ Wdt^T + bias), f32 exact.
// ---------------------------------------------------------------------------
__global__ __launch_bounds__(256) void dt_gemm(
    const float* __restrict__ x, const float* __restrict__ WdtT,
    const float* __restrict__ dt_bias, float* __restrict__ dtb) {
  __shared__ alignas(16) float Xs[4][1024];   // 16 KB
  __shared__ float Ps[4][8][32];              // 4 KB
  const int tid = threadIdx.x;
  const int gm0 = blockIdx.x * 4;
#pragma unroll
  for (int q = 0; q < 4; ++q)
    *(f4*)&Xs[q][tid * 4 - (tid >> 8)] = *(const f4*)(x + (size_t)(gm0 + q) * kDM + tid * 4);
  __syncthreads();

  const int h  = tid & 31;
  const int sl = tid >> 5;
  const int k0 = sl * 128;
  float p0 = 0.f, p1 = 0.f, p2 = 0.f, p3 = 0.f;
#pragma unroll 8
  for (int i = 0; i < 128; ++i) {
    const float w = WdtT[(k0 + i) * 32 + h];
    p0 = fmaf(Xs[0][k0 + i], w, p0);
    p1 = fmaf(Xs[1][k0 + i], w, p1);
    p2 = fmaf(Xs[2][k0 + i], w, p2);
    p3 = fmaf(Xs[3][k0 + i], w, p3);
  }
  Ps[0][sl][h] = p0; Ps[1][sl][h] = p1; Ps[2][sl][h] = p2; Ps[3][sl][h] = p3;
  __syncthreads();
  if (tid < 128) {
    const int r = tid >> 5, hh = tid & 31;
    float v = 0.f;
#pragma unroll
    for (int s2 = 0; s2 < 8; ++s2) v += Ps[r][s2][hh];
    const float dtp = v + dt_bias[hh];
    const float dt  = (dtp > 20.f) ? dtp : log1pf(__expf(dtp));
    const int gm = gm0 + r;
    dtb[(size_t)((gm >> 10) * 32 + hh) * kL + (gm & 1023)] = dt;
  }
}

// ---------------------------------------------------------------------------
// K2: f16 GEMM, BM=128 x BN=256 tile, 512 thr (8 waves), BK=32, dbuf
// prefetch, T2 XOR-swizzle, XCD swizzle. Unchanged from R10 (measured win).
// ---------------------------------------------------------------------------
__global__ __launch_bounds__(512) void gemm1(
    const _Float16* __restrict__ A, const _Float16* __restrict__ Bm,
    _Float16* __restrict__ C, int M, int N, int K) {
  __shared__ alignas(16) _Float16 As[2][128][32];
  __shared__ alignas(16) _Float16 Bs[2][256][32];
  const int tid  = threadIdx.x;      // 0..511
  const int lane = tid & 63;
  const int w    = tid >> 6;         // 0..7
  const int id   = blockIdx.x;
  const int sw   = (id & 7) * 64 + (id >> 3);    // XCD swizzle (nwg=512)
  const int m0   = (sw & 15) * 128;              // 16 M tiles
  const int n0   = (sw >> 4) * 256;              // 32 N tiles
  const int ar   = tid >> 2;                     // staging row 0..127
  const int cc   = (tid & 3) * 8;                            // linear LDS chunk
  const int ccs  = (((tid & 3) ^ ((tid >> 3) & 3))) * 8;     // swizzled global chunk
  const int wm   = (w & 1) * 64;                 // wave M offset (2 x 64)
  const int wn   = (w >> 1) * 64;                // wave N offset (4 x 64)
  const int l16  = lane & 15;
  const int l4   = lane >> 4;
  const int rsw  = (l16 >> 1) & 3;               // read-side XOR key

  f4 acc[4][4] = {};

  auto stage = [&](int buf, int k0) {
    async_ld16(A  + (size_t)(m0 + ar) * K + (k0 + ccs), &As[buf][ar][cc]);
    async_ld16(Bm + (size_t)(n0 + ar) * K + (k0 + ccs), &Bs[buf][ar][cc]);
    async_ld16(Bm + (size_t)(n0 + 128 + ar) * K + (k0 + ccs), &Bs[buf][128 + ar][cc]);
  };
  auto compute = [&](int buf) {
    f16x8 af[4], bf[4];
#pragma unroll
    for (int t = 0; t < 4; ++t) {
      af[t] = *reinterpret_cast<const f16x8*>(&As[buf][wm + t * 16 + l16][(l4 ^ rsw) * 8]);
      bf[t] = *reinterpret_cast<const f16x8*>(&Bs[buf][wn + t * 16 + l16][(l4 ^ rsw) * 8]);
    }
#pragma unroll
    for (int i = 0; i < 4; ++i)
#pragma unroll
      for (int j = 0; j < 4; ++j)
        acc[i][j] = __builtin_amdgcn_mfma_f32_16x16x32_f16(af[i], bf[j], acc[i][j], 0, 0, 0);
  };

  stage(0, 0);
  __syncthreads();
  int cur = 0;
  for (int k0 = 0; k0 < K - 32; k0 += 32) {
    stage(cur ^ 1, k0 + 32);   // next tile in flight during compute
    compute(cur);
    __syncthreads();           // drains vmcnt(0): next buffer ready
    cur ^= 1;
  }
  compute(cur);                // last tile, no prefetch

  const int col = l16;      // C/D: col = lane&15, row = (lane>>4)*4 + reg
  const int r0  = l4 * 4;
#pragma unroll
  for (int i = 0; i < 4; ++i)
#pragma unroll
    for (int j = 0; j < 4; ++j) {
      const int gn = n0 + wn + j * 16 + col;
#pragma unroll
      for (int r = 0; r < 4; ++r) {
        const int gm = m0 + wm + i * 16 + r0 + r;
        C[(size_t)gm * N + gn] = (_Float16)acc[i][j][r];
      }
    }
}

// ---------------------------------------------------------------------------
// K3: scan pass 1. 2 heads per 256-thr block. Lane map: g=lane>>3 owns
// s in [8g,8g+8), dd=lane&7 owns d0=wd*32+dd*4 (4 d). 5 DS instr/wave-t.
// No cross-lane reduce needed here -> pure win (R11 measured).
// ---------------------------------------------------------------------------
__global__ __launch_bounds__(256) void scan_pass1(
    const _Float16* __restrict__ proj16, const float* __restrict__ dtb,
    const float* __restrict__ negA, const float* __restrict__ conv_w,
    const float* __restrict__ conv_b, float* __restrict__ H,
    float* __restrict__ sdt) {
  __shared__ alignas(16) float Ad[2][kQH][64];   // 8 KB
  __shared__ alignas(16) float Bd[2][kQH][64];   // 8 KB
  __shared__ alignas(16) float Xd[2][kQH][64];   // 8 KB (xdt f32)
  __shared__ float dts[2][kQ];
  const int tid  = threadIdx.x;
  const int g    = blockIdx.x;
  const int c    = g & (kNC - 1);
  const int bnp  = g >> 5;
  const int lane = tid & 63;
  const int w    = tid >> 6;
  const int hb   = w >> 1;
  const int wd   = w & 1;
  const int sg8  = lane >> 3;      // s-group (8 s each)
  const int dd   = lane & 7;
  const int bn   = bnp * 2 + hb;
  const int l0   = c * kQ;
  const int d0   = wd * 32 + dd * 4;
  const int t128 = tid & 127;
  const int shb  = tid >> 7;   // staging: which head this thread serves

  f4 h[8] = {};

  for (int p = 0; p < 2; ++p) {
    const int r0 = p * kQH;
    // ---- stage (128 thr per head): row = t128>>3, 8-ch slice ----
    {
      const int sn  = (bnp * 2 + shb) & 31;
      const int sb  = (bnp * 2 + shb) >> 5;
      const int row = t128 >> 3;
      const int ch  = (t128 & 7) * 8;
      const int gl  = l0 + r0 + row;
      const float dtl = dtb[(size_t)(bnp * 2 + shb) * kL + gl];
      if ((t128 & 7) == 0) dts[shb][r0 + row] = dtl;
      // B: f16 -> f32
      const f16x8 vb = *(const f16x8*)(proj16 +
          (size_t)(sb * kL + gl) * kPROJW + 4096 + sn * 64 + ch);
      f4 blo, bhi;
      blo[0]=(float)vb[0]; blo[1]=(float)vb[1]; blo[2]=(float)vb[2]; blo[3]=(float)vb[3];
      bhi[0]=(float)vb[4]; bhi[1]=(float)vb[5]; bhi[2]=(float)vb[6]; bhi[3]=(float)vb[7];
      *(f4*)&Bd[shb][row][ch]     = blo;
      *(f4*)&Bd[shb][row][ch + 4] = bhi;
      // A: exp
#pragma unroll
      for (int j = 0; j < 8; ++j)
        Ad[shb][row][ch + j] = __expf(negA[sn * 64 + ch + j] * dtl);
      // conv + silu -> xdt (f32)
      float acc[8];
#pragma unroll
      for (int j = 0; j < 8; ++j) acc[j] = conv_b[sn * 64 + ch + j];
#pragma unroll
      for (int jj = 0; jj < 4; ++jj) {
        const int r = gl - 3 + jj;
        if (r < 0) continue;
        const f16x8 v0 = *(const f16x8*)(proj16 + (size_t)(sb * kL + r) * kPROJW + sn * 64 + ch);
#pragma unroll
        for (int j = 0; j < 8; ++j)
          acc[j] += conv_w[(sn * 64 + ch + j) * 4 + jj] * (float)v0[j];
      }
#pragma unroll
      for (int j = 0; j < 8; ++j)
        Xd[shb][row][ch + j] = dtl * (acc[j] * sigm(acc[j]));
    }
    __syncthreads();

    // ---- compute ----
#pragma unroll 2
    for (int tt = 0; tt < kQH; ++tt) {
      const f4 xv = *(const f4*)&Xd[hb][tt][d0];
      const f4 a0 = ((const f4*)&Ad[hb][tt][sg8 * 8])[0];
      const f4 a1 = ((const f4*)&Ad[hb][tt][sg8 * 8])[1];
      const f4 b0 = ((const f4*)&Bd[hb][tt][sg8 * 8])[0];
      const f4 b1 = ((const f4*)&Bd[hb][tt][sg8 * 8])[1];
#pragma unroll
      for (int si = 0; si < 4; ++si) {
        h[si]     = a0[si] * h[si]     + b0[si] * xv;
        h[si + 4] = a1[si] * h[si + 4] + b1[si] * xv;
      }
    }
    __syncthreads();
  }

  if (t128 == 0) {     // tid 0 -> head 0, tid 128 -> head 1
    float s = 0.f;
    for (int t = 0; t < kQ; ++t) s += dts[shb][t];
    sdt[(bnp * 2 + shb) * kNC + c] = s;
  }

  float* hp = H + (((size_t)bn * kNC + c) * 64 + sg8 * 8) * 64 + d0;
#pragma unroll
  for (int si = 0; si < 8; ++si)
    *(f4*)&hp[(size_t)si * 64] = h[si];
}

// ---------------------------------------------------------------------------
// K4: chunk stitching IN-PLACE, scalar-d regrid: 1024 blocks x 256 thr,
// thread = (s = sq*4 + tid>>6, d = tid&63); 256B coalesced rows, 4x TLP.
// ---------------------------------------------------------------------------
__global__ __launch_bounds__(256) void scan_pass2(
    float* __restrict__ H, const float* __restrict__ sdt,
    const float* __restrict__ negA) {
  const int bn = blockIdx.x >> 4;       // 64
  const int sq = blockIdx.x & 15;       // 16
  const int s  = sq * 4 + (threadIdx.x >> 6);
  const int d  = threadIdx.x & 63;
  const int n  = bn & 31;
  const float Aa = negA[n * 64 + s];
  float h = 0.f;
  for (int c = 0; c < kNC; ++c) {
    const size_t off = (((size_t)bn * kNC + c) * 64 + s) * 64 + d;
    const float ap = __expf(Aa * sdt[bn * kNC + c]);
    const float hl = H[off];   // local sums
    H[off] = h;                // overwrite with carry-in
    h = ap * h + hl;
  }
}

// ---------------------------------------------------------------------------
// K5: scan pass 3. REVERTED to the R10 16s x 2d lane map (measured 46.4 us):
// the 8s x 4d map's 12 shuffles/t cost more than its 6 saved b128 reads
// (R11: 53.4 us). sg=lane>>4 owns 16 s, dd=lane&15 owns d0..d0+1.
// 2-head packing, all-f32 A/B/C/X LDS, 4 shuffles/t reduce.
// ---------------------------------------------------------------------------
__global__ __launch_bounds__(256) void scan_pass3(
    const _Float16* __restrict__ proj16, const float* __restrict__ dtb,
    const float* __restrict__ negA, const float* __restrict__ conv_w,
    const float* __restrict__ conv_b, const float* __restrict__ H,
    const float* __restrict__ Dv, _Float16* __restrict__ yin) {
  __shared__ alignas(16) float Ad[2][kQH][64];     // 8 KB
  __shared__ alignas(16) float Bd[2][kQH][64];     // 8 KB
  __shared__ alignas(16) float Cd[2][kQH][64];     // 8 KB
  __shared__ alignas(16) float Xd[2][kQH][64];     // 8 KB (xdt f32)
  __shared__ alignas(16) _Float16 Xs[2][kQH][64];  // 2 KB (xsilu f16)
  __shared__ alignas(16) _Float16 Zd[2][kQH][64];  // 2 KB (raw z)
  const int tid  = threadIdx.x;
  const int g    = blockIdx.x;
  const int c    = g & (kNC - 1);
  const int bnp  = g >> 5;
  const int lane = tid & 63;
  const int w    = tid >> 6;
  const int hb   = w >> 1;
  const int wd   = w & 1;
  const int sg   = lane >> 4;
  const int dd   = lane & 15;
  const int bn   = bnp * 2 + hb;
  const int b    = bn >> 5, n = bn & 31;
  const int l0   = c * kQ;
  const int d0   = wd * 32 + dd * 2;
  const int t128 = tid & 127;
  const int shb  = tid >> 7;

  // h init from carry-in (registers, carried across both phases)
  f4 hA[4], hB[4];
  {
    const float* hp = H + (((size_t)bn * kNC + c) * 64 + sg * 16) * 64 + d0;
#pragma unroll
    for (int q = 0; q < 4; ++q)
#pragma unroll
      for (int i = 0; i < 4; ++i) {
        const f2 hv = *(const f2*)&hp[(size_t)(q * 4 + i) * 64];
        hA[q][i] = hv[0]; hB[q][i] = hv[1];
      }
  }
  const float Dn = Dv[n];
  _Float16* Yb = yin + (size_t)(b * kL + l0) * kDI + n * 64 + d0;

  for (int p = 0; p < 2; ++p) {
    const int r0 = p * kQH;
    // ---- stage (128 thr per head) ----
    {
      const int sn  = (bnp * 2 + shb) & 31;
      const int sb  = (bnp * 2 + shb) >> 5;
      const int row = t128 >> 3;
      const int ch  = (t128 & 7) * 8;
      const int gl  = l0 + r0 + row;
      const _Float16* base = proj16 + (size_t)(sb * kL + gl) * kPROJW + sn * 64 + ch;
      async_ld16(base + 2048, &Zd[shb][row][ch]);
      const float dtl = dtb[(size_t)(bnp * 2 + shb) * kL + gl];
      // B, C: f16 -> f32
      const f16x8 vb = *(const f16x8*)(base + 4096);
      const f16x8 vc = *(const f16x8*)(base + 6144);
      f4 blo, bhi, clo, chi;
      blo[0]=(float)vb[0]; blo[1]=(float)vb[1]; blo[2]=(float)vb[2]; blo[3]=(float)vb[3];
      bhi[0]=(float)vb[4]; bhi[1]=(float)vb[5]; bhi[2]=(float)vb[6]; bhi[3]=(float)vb[7];
      clo[0]=(float)vc[0]; clo[1]=(float)vc[1]; clo[2]=(float)vc[2]; clo[3]=(float)vc[3];
      chi[0]=(float)vc[4]; chi[1]=(float)vc[5]; chi[2]=(float)vc[6]; chi[3]=(float)vc[7];
      *(f4*)&Bd[shb][row][ch]     = blo;
      *(f4*)&Bd[shb][row][ch + 4] = bhi;
      *(f4*)&Cd[shb][row][ch]     = clo;
      *(f4*)&Cd[shb][row][ch + 4] = chi;
      // A: exp
#pragma unroll
      for (int j = 0; j < 8; ++j)
        Ad[shb][row][ch + j] = __expf(negA[sn * 64 + ch + j] * dtl);
      // conv + silu -> xsilu (f16) and xdt (f32)
      float acc[8];
#pragma unroll
      for (int j = 0; j < 8; ++j) acc[j] = conv_b[sn * 64 + ch + j];
#pragma unroll
      for (int jj = 0; jj < 4; ++jj) {
        const int r = gl - 3 + jj;
        if (r < 0) continue;
        const f16x8 v0 = *(const f16x8*)(proj16 + (size_t)(sb * kL + r) * kPROJW + sn * 64 + ch);
#pragma unroll
        for (int j = 0; j < 8; ++j)
          acc[j] += conv_w[(sn * 64 + ch + j) * 4 + jj] * (float)v0[j];
      }
      f16x8 xo;
#pragma unroll
      for (int j = 0; j < 8; ++j) {
        const float xs = acc[j] * sigm(acc[j]);
        xo[j] = (_Float16)xs;
        Xd[shb][row][ch + j] = dtl * xs;
      }
      *(f16x8*)&Xs[shb][row][ch] = xo;
    }
    __syncthreads();

    // ---- compute ----
#pragma unroll 2
    for (int tt = 0; tt < kQH; ++tt) {
      const f2 xv = *(const f2*)&Xd[hb][tt][d0];
      const float x0 = xv[0], x1 = xv[1];
      f4 pvA = {}, pvB = {};
#pragma unroll
      for (int q = 0; q < 4; ++q) {
        const f4 a  = ((const f4*)&Ad[hb][tt][sg * 16])[q];
        const f4 bb = ((const f4*)&Bd[hb][tt][sg * 16])[q];
        const f4 cc = ((const f4*)&Cd[hb][tt][sg * 16])[q];
        hA[q] = a * hA[q] + bb * x0;
        hB[q] = a * hB[q] + bb * x1;
        pvA = pvA + cc * hA[q];
        pvB = pvB + cc * hB[q];
      }
      float pA = (pvA[0] + pvA[1]) + (pvA[2] + pvA[3]);
      float pB = (pvB[0] + pvB[1]) + (pvB[2] + pvB[3]);
      pA += __shfl_xor(pA, 16);
      pA += __shfl_xor(pA, 32);
      pB += __shfl_xor(pB, 16);
      pB += __shfl_xor(pB, 32);
      if (sg == 0) {
        const f16x2 zv = *(const f16x2*)&Zd[hb][tt][d0];
        const f16x2 xs = *(const f16x2*)&Xs[hb][tt][d0];
        const float z0 = (float)zv[0], z1 = (float)zv[1];
        const float y0 = (pA + Dn * (float)xs[0]) * (z0 * sigm(z0));
        const float y1 = (pB + Dn * (float)xs[1]) * (z1 * sigm(z1));
        f16x2 yv; yv[0] = (_Float16)y0; yv[1] = (_Float16)y1;
        *(f16x2*)&Yb[(size_t)(r0 + tt) * kDI] = yv;
      }
    }
    __syncthreads();
  }
}

// ---------------------------------------------------------------------------
// K6: out[2048,1024] f32 = yin @ Wo16^T. 64x64 tile, BK=32, dbuf prefetch,
// XCD swizzle (nwg=512), XOR-swizzle. Unchanged.
// ---------------------------------------------------------------------------
__global__ __launch_bounds__(256) void gemm_out(
    const _Float16* __restrict__ A, const _Float16* __restrict__ Bm,
    float* __restrict__ C) {
  __shared__ alignas(16) _Float16 As[2][64][32];
  __shared__ alignas(16) _Float16 Bs[2][64][32];
  const int tid  = threadIdx.x;
  const int lane = tid & 63;
  const int w    = tid >> 6;
  const int id   = blockIdx.x;
  const int sw   = (id & 7) * 64 + (id >> 3);    // XCD swizzle (nwg=512)
  const int m0   = (sw >> 4) * 64;               // 32 M-tiles
  const int n0   = (sw & 15) * 64;               // 16 N-tiles
  const int row  = tid >> 2;
  const int cc   = (tid & 3) * 8;                          // linear LDS chunk
  const int ccs  = (((lane & 3) ^ ((lane >> 3) & 3))) * 8; // swizzled global chunk
  const int wm   = (w & 1) * 32;
  const int wn   = (w >> 1) * 32;
  const int l16  = lane & 15;
  const int l4   = lane >> 4;
  const int rsw  = (l16 >> 1) & 3;                         // read-side XOR

  f4 acc[2][2] = {};

  auto stage = [&](int buf, int k0) {
    async_ld16(A + (size_t)(m0 + row) * kDI + (k0 + ccs), &As[buf][row][cc]);
    async_ld16(Bm + (size_t)(n0 + row) * kDI + (k0 + ccs), &Bs[buf][row][cc]);
  };
  auto compute = [&](int buf) {
    f16x8 af[2], bf[2];
#pragma unroll
    for (int t = 0; t < 2; ++t) {
      af[t] = *reinterpret_cast<const f16x8*>(&As[buf][wm + t * 16 + l16][(l4 ^ rsw) * 8]);
      bf[t] = *reinterpret_cast<const f16x8*>(&Bs[buf][wn + t * 16 + l16][(l4 ^ rsw) * 8]);
    }
#pragma unroll
    for (int i = 0; i < 2; ++i)
#pragma unroll
      for (int j = 0; j < 2; ++j)
        acc[i][j] = __builtin_amdgcn_mfma_f32_16x16x32_f16(af[i], bf[j], acc[i][j], 0, 0, 0);
  };

  stage(0, 0);
  __syncthreads();
  int cur = 0;
  for (int k0 = 0; k0 < kDI - 32; k0 += 32) {
    stage(cur ^ 1, k0 + 32);
    compute(cur);
    __syncthreads();
    cur ^= 1;
  }
  compute(cur);

  const int col = l16;
  const int r0  = l4 * 4;
#pragma unroll
  for (int i = 0; i < 2; ++i)
#pragma unroll
    for (int j = 0; j < 2; ++j) {
      const int gn = n0 + wn + j * 16 + col;
#pragma unroll
      for (int r = 0; r < 4; ++r) {
        const int gm = m0 + wm + i * 16 + r0 + r;
        C[(size_t)gm * kDM + gn] = acc[i][j][r];
      }
    }
}

// ---------------------------------------------------------------------------
extern "C" void kernel_launch(void* const* d_in, const int* in_sizes, int n_in,
                              void* d_out, int out_size, void* d_ws, size_t ws_size,
                              hipStream_t stream) {
  const float* x      = (const float*)d_in[0];
  const float* W_in   = (const float*)d_in[1];
  const float* conv_w = (const float*)d_in[2];
  const float* conv_b = (const float*)d_in[3];
  const float* A_log  = (const float*)d_in[4];
  const float* Dv     = (const float*)d_in[5];
  const float* dt_b   = (const float*)d_in[6];
  const float* W_out  = (const float*)d_in[7];
  float* out = (float*)d_out;

  char* p = (char*)d_ws;
  _Float16* proj16 = (_Float16*)p; p += (size_t)kBL * kPROJW * 2;   // 33.6 MB
  float* dtb   = (float*)p; p += (size_t)64 * kL * 4;
  float* negA  = (float*)p; p += 2048 * 4;
  float* WdtT  = (float*)p; p += (size_t)1024 * 32 * 4;             // 128 KB
  float* sdt   = (float*)p; p += (size_t)64 * kNC * 4 + 3968;       // 8 KB + pad
  float* H     = (float*)p; p += (size_t)64 * kNC * 64 * 64 * 4;    // 33.6 MB (local sums -> carry-ins, in place)
  _Float16* yin  = (_Float16*)p; p += (size_t)kBL * kDI * 2;        // 8.4 MB
  _Float16* Wo16 = (_Float16*)p; p += (size_t)kDM * kDI * 2;        // 4.2 MB
  _Float16* x16  = (_Float16*)H;                    // alias (pre-scan phase)
  _Float16* Wi16 = x16 + (size_t)kBL * kDM;         // 16.8 MB, fits in H (33.6)

  prep_inputs<<<kCvtBlocks + kNegABlocks, 256, 0, stream>>>(
      x, W_in, W_out, A_log, x16, Wi16, Wo16, WdtT, negA);

  dt_gemm<<<kBL / 4, 256, 0, stream>>>(x, WdtT, dt_b, dtb);

  gemm1<<<(kBL / 128) * (kPROJW / 256), 512, 0, stream>>>(
      x16, Wi16, proj16, kBL, kPROJW, kDM);

  scan_pass1<<<(64 / 2) * kNC, 256, 0, stream>>>(proj16, dtb, negA, conv_w, conv_b, H, sdt);
  scan_pass2<<<64 * 16, 256, 0, stream>>>(H, sdt, negA);
  scan_pass3<<<(64 / 2) * kNC, 256, 0, stream>>>(proj16, dtb, negA, conv_w, conv_b, H, Dv, yin);

  gemm_out<<<(kBL / 64) * (kDM / 64), 256, 0, stream>>>(yin, Wo16, out);
}

// Round 13
// 268.688 us; speedup vs baseline: 1.1388x; 1.0448x over previous
//
#include <hip/hip_runtime.h>
#include <hip/hip_fp16.h>

namespace {
constexpr int kB  = 2;
constexpr int kL  = 1024;
constexpr int kDM = 1024;
constexpr int kDI = 2048;
constexpr int kPROJW = 8192;   // proj16 row: [x 0..2048 | z ..4096 | B ..6144 | C ..8192]
constexpr int kBL = 2048;
constexpr int kQ  = 32;        // chunk length
constexpr int kQH = 16;        // rows staged per phase
constexpr int kNC = 32;        // chunks per (b,n)
constexpr int kCvtX = kBL * kDM / 4;      // 524288 vec4
constexpr int kCvtW = 8192 * kDM / 4;     // 2097152 (WdtT pack removed)
constexpr int kCvtO = kDM * kDI / 4;      // 524288
constexpr int kCvtBlocks  = (kCvtX + kCvtW + kCvtO) / 256;  // 12288
constexpr int kNegABlocks = 8;
constexpr int kDtBlocks   = kBL / 4;      // 512 fused dt-gemm blocks
}

typedef float f4 __attribute__((ext_vector_type(4)));
typedef float f2 __attribute__((ext_vector_type(2)));
typedef _Float16 f16x8 __attribute__((ext_vector_type(8)));
typedef _Float16 f16x4 __attribute__((ext_vector_type(4)));
typedef _Float16 f16x2 __attribute__((ext_vector_type(2)));

__device__ __forceinline__ void async_ld16(const void* g, void* l) {
  __builtin_amdgcn_global_load_lds(
      (const __attribute__((address_space(1))) void*)g,
      (__attribute__((address_space(3))) void*)l, 16, 0, 0);
}

__device__ __forceinline__ float sigm(float v) {
  return __builtin_amdgcn_rcpf(1.f + __expf(-v));   // 1-instr rcp vs IEEE div
}

// ---------------------------------------------------------------------------
// K1 (fused): f32->f16 cvt of x / W_in / W_out + negA + dt_gemm.
// dt blocks read W_in dt-rows directly (L2-hot 128 KB), transposing k-tiles
// through LDS -> no WdtT dependency, dt work overlaps BW-bound cvt blocks.
// ---------------------------------------------------------------------------
__global__ __launch_bounds__(256) void prep_inputs(
    const float* __restrict__ x, const float* __restrict__ W_in,
    const float* __restrict__ W_out, const float* __restrict__ A_log,
    const float* __restrict__ dt_bias,
    _Float16* __restrict__ x16, _Float16* __restrict__ Wi16,
    _Float16* __restrict__ Wo16, float* __restrict__ negA,
    float* __restrict__ dtb) {
  __shared__ alignas(16) float Xs2[4][1024];   // 16 KB   (dt path)
  __shared__ alignas(16) float Wk[128][33];    // 16.9 KB (dt path, transposed tile)
  __shared__ float Ps[4][8][32];               // 4 KB    (dt path)
  const int bid = blockIdx.x;
  const int tid = threadIdx.x;
  if (bid < kCvtBlocks) {
    int i = bid * 256 + tid;
    if (i < kCvtX) {
      const f4 v = ((const f4*)x)[i];
      f16x4 o; o[0]=(_Float16)v[0]; o[1]=(_Float16)v[1]; o[2]=(_Float16)v[2]; o[3]=(_Float16)v[3];
      ((f16x4*)x16)[i] = o;
    } else if (i < kCvtX + kCvtW) {
      i -= kCvtX;
      const int row = i >> 8;        // [0, 8192)
      const int cv  = i & 255;
      int srow;
      if (row < 4096)      srow = row;
      else if (row < 6144) { const int m = row - 4096; srow = 4096 + (m >> 6) * 129 + (m & 63); }
      else                 { const int m = row - 6144; srow = 4096 + (m >> 6) * 129 + 64 + (m & 63); }
      const f4 v = ((const f4*)(W_in + (size_t)srow * kDM))[cv];
      f16x4 o; o[0]=(_Float16)v[0]; o[1]=(_Float16)v[1]; o[2]=(_Float16)v[2]; o[3]=(_Float16)v[3];
      ((f16x4*)(Wi16 + (size_t)row * kDM))[cv] = o;
    } else {
      i -= kCvtX + kCvtW;
      const f4 v = ((const f4*)W_out)[i];
      f16x4 o; o[0]=(_Float16)v[0]; o[1]=(_Float16)v[1]; o[2]=(_Float16)v[2]; o[3]=(_Float16)v[3];
      ((f16x4*)Wo16)[i] = o;
    }
  } else if (bid < kCvtBlocks + kNegABlocks) {
    const int i = (bid - kCvtBlocks) * 256 + tid;
    if (i < 2048) negA[i] = -__expf(A_log[i]);
  } else {
    // ---- dt_gemm: dtb = softplus(x @ Wdt^T + bias), f32 exact ----
    const int gm0 = (bid - kCvtBlocks - kNegABlocks) * 4;
#pragma unroll
    for (int q = 0; q < 4; ++q)
      *(f4*)&Xs2[q][tid * 4] = *(const f4*)(x + (size_t)(gm0 + q) * kDM + tid * 4);
    const int h    = tid & 31;
    const int sl   = tid >> 5;
    const int wh   = tid >> 3;          // W dt-row 0..31
    const int part = tid & 7;
    const size_t srow = (size_t)(4096 + wh * 129 + 128) * kDM;
    float p0 = 0.f, p1 = 0.f, p2 = 0.f, p3 = 0.f;
    __syncthreads();
    for (int kt = 0; kt < 8; ++kt) {
      // load+transpose W tile: 32 rows x 128 k -> Wk[k][h]
#pragma unroll
      for (int j = 0; j < 4; ++j) {
        const f4 v = *(const f4*)(W_in + srow + kt * 128 + part * 16 + j * 4);
#pragma unroll
        for (int e = 0; e < 4; ++e) Wk[part * 16 + j * 4 + e][wh] = v[e];
      }
      __syncthreads();
      const int kb = kt * 128 + sl * 16;
#pragma unroll
      for (int i2 = 0; i2 < 16; ++i2) {
        const float wv = Wk[sl * 16 + i2][h];
        p0 = fmaf(Xs2[0][kb + i2], wv, p0);
        p1 = fmaf(Xs2[1][kb + i2], wv, p1);
        p2 = fmaf(Xs2[2][kb + i2], wv, p2);
        p3 = fmaf(Xs2[3][kb + i2], wv, p3);
      }
      __syncthreads();
    }
    Ps[0][sl][h] = p0; Ps[1][sl][h] = p1; Ps[2][sl][h] = p2; Ps[3][sl][h] = p3;
    __syncthreads();
    if (tid < 128) {
      const int r = tid >> 5, hh = tid & 31;
      float v = 0.f;
#pragma unroll
      for (int s2 = 0; s2 < 8; ++s2) v += Ps[r][s2][hh];
      const float dtp = v + dt_bias[hh];
      const float dt  = (dtp > 20.f) ? dtp : log1pf(__expf(dtp));
      const int gm = gm0 + r;
      dtb[(size_t)((gm >> 10) * 32 + hh) * kL + (gm & 1023)] = dt;
    }
  }
}

// ---------------------------------------------------------------------------
// K2: f16 GEMM, BM=128 x BN=256 tile, 512 thr (8 waves), BK=32, dbuf
// prefetch, T2 XOR-swizzle, XCD swizzle. Unchanged from R10 (measured win).
// ---------------------------------------------------------------------------
__global__ __launch_bounds__(512) void gemm1(
    const _Float16* __restrict__ A, const _Float16* __restrict__ Bm,
    _Float16* __restrict__ C, int M, int N, int K) {
  __shared__ alignas(16) _Float16 As[2][128][32];
  __shared__ alignas(16) _Float16 Bs[2][256][32];
  const int tid  = threadIdx.x;      // 0..511
  const int lane = tid & 63;
  const int w    = tid >> 6;         // 0..7
  const int id   = blockIdx.x;
  const int sw   = (id & 7) * 64 + (id >> 3);    // XCD swizzle (nwg=512)
  const int m0   = (sw & 15) * 128;              // 16 M tiles
  const int n0   = (sw >> 4) * 256;              // 32 N tiles
  const int ar   = tid >> 2;                     // staging row 0..127
  const int cc   = (tid & 3) * 8;                            // linear LDS chunk
  const int ccs  = (((tid & 3) ^ ((tid >> 3) & 3))) * 8;     // swizzled global chunk
  const int wm   = (w & 1) * 64;                 // wave M offset (2 x 64)
  const int wn   = (w >> 1) * 64;                // wave N offset (4 x 64)
  const int l16  = lane & 15;
  const int l4   = lane >> 4;
  const int rsw  = (l16 >> 1) & 3;               // read-side XOR key

  f4 acc[4][4] = {};

  auto stage = [&](int buf, int k0) {
    async_ld16(A  + (size_t)(m0 + ar) * K + (k0 + ccs), &As[buf][ar][cc]);
    async_ld16(Bm + (size_t)(n0 + ar) * K + (k0 + ccs), &Bs[buf][ar][cc]);
    async_ld16(Bm + (size_t)(n0 + 128 + ar) * K + (k0 + ccs), &Bs[buf][128 + ar][cc]);
  };
  auto compute = [&](int buf) {
    f16x8 af[4], bf[4];
#pragma unroll
    for (int t = 0; t < 4; ++t) {
      af[t] = *reinterpret_cast<const f16x8*>(&As[buf][wm + t * 16 + l16][(l4 ^ rsw) * 8]);
      bf[t] = *reinterpret_cast<const f16x8*>(&Bs[buf][wn + t * 16 + l16][(l4 ^ rsw) * 8]);
    }
#pragma unroll
    for (int i = 0; i < 4; ++i)
#pragma unroll
      for (int j = 0; j < 4; ++j)
        acc[i][j] = __builtin_amdgcn_mfma_f32_16x16x32_f16(af[i], bf[j], acc[i][j], 0, 0, 0);
  };

  stage(0, 0);
  __syncthreads();
  int cur = 0;
  for (int k0 = 0; k0 < K - 32; k0 += 32) {
    stage(cur ^ 1, k0 + 32);   // next tile in flight during compute
    compute(cur);
    __syncthreads();           // drains vmcnt(0): next buffer ready
    cur ^= 1;
  }
  compute(cur);                // last tile, no prefetch

  const int col = l16;      // C/D: col = lane&15, row = (lane>>4)*4 + reg
  const int r0  = l4 * 4;
#pragma unroll
  for (int i = 0; i < 4; ++i)
#pragma unroll
    for (int j = 0; j < 4; ++j) {
      const int gn = n0 + wn + j * 16 + col;
#pragma unroll
      for (int r = 0; r < 4; ++r) {
        const int gm = m0 + wm + i * 16 + r0 + r;
        C[(size_t)gm * N + gn] = (_Float16)acc[i][j][r];
      }
    }
}

// ---------------------------------------------------------------------------
// K3: scan pass 1. 2 heads per 256-thr block. Lane map: g=lane>>3 owns
// s in [8g,8g+8), dd=lane&7 owns d0=wd*32+dd*4. Unchanged from R12.
// ---------------------------------------------------------------------------
__global__ __launch_bounds__(256) void scan_pass1(
    const _Float16* __restrict__ proj16, const float* __restrict__ dtb,
    const float* __restrict__ negA, const float* __restrict__ conv_w,
    const float* __restrict__ conv_b, float* __restrict__ H,
    float* __restrict__ sdt) {
  __shared__ alignas(16) float Ad[2][kQH][64];   // 8 KB
  __shared__ alignas(16) float Bd[2][kQH][64];   // 8 KB
  __shared__ alignas(16) float Xd[2][kQH][64];   // 8 KB (xdt f32)
  __shared__ float dts[2][kQ];
  const int tid  = threadIdx.x;
  const int g    = blockIdx.x;
  const int c    = g & (kNC - 1);
  const int bnp  = g >> 5;
  const int lane = tid & 63;
  const int w    = tid >> 6;
  const int hb   = w >> 1;
  const int wd   = w & 1;
  const int sg8  = lane >> 3;      // s-group (8 s each)
  const int dd   = lane & 7;
  const int bn   = bnp * 2 + hb;
  const int l0   = c * kQ;
  const int d0   = wd * 32 + dd * 4;
  const int t128 = tid & 127;
  const int shb  = tid >> 7;   // staging: which head this thread serves

  f4 h[8] = {};

  for (int p = 0; p < 2; ++p) {
    const int r0 = p * kQH;
    // ---- stage (128 thr per head): row = t128>>3, 8-ch slice ----
    {
      const int sn  = (bnp * 2 + shb) & 31;
      const int sb  = (bnp * 2 + shb) >> 5;
      const int row = t128 >> 3;
      const int ch  = (t128 & 7) * 8;
      const int gl  = l0 + r0 + row;
      const float dtl = dtb[(size_t)(bnp * 2 + shb) * kL + gl];
      if ((t128 & 7) == 0) dts[shb][r0 + row] = dtl;
      // B: f16 -> f32
      const f16x8 vb = *(const f16x8*)(proj16 +
          (size_t)(sb * kL + gl) * kPROJW + 4096 + sn * 64 + ch);
      f4 blo, bhi;
      blo[0]=(float)vb[0]; blo[1]=(float)vb[1]; blo[2]=(float)vb[2]; blo[3]=(float)vb[3];
      bhi[0]=(float)vb[4]; bhi[1]=(float)vb[5]; bhi[2]=(float)vb[6]; bhi[3]=(float)vb[7];
      *(f4*)&Bd[shb][row][ch]     = blo;
      *(f4*)&Bd[shb][row][ch + 4] = bhi;
      // A: exp
#pragma unroll
      for (int j = 0; j < 8; ++j)
        Ad[shb][row][ch + j] = __expf(negA[sn * 64 + ch + j] * dtl);
      // conv + silu -> xdt (f32)
      float acc[8];
#pragma unroll
      for (int j = 0; j < 8; ++j) acc[j] = conv_b[sn * 64 + ch + j];
#pragma unroll
      for (int jj = 0; jj < 4; ++jj) {
        const int r = gl - 3 + jj;
        if (r < 0) continue;
        const f16x8 v0 = *(const f16x8*)(proj16 + (size_t)(sb * kL + r) * kPROJW + sn * 64 + ch);
#pragma unroll
        for (int j = 0; j < 8; ++j)
          acc[j] += conv_w[(sn * 64 + ch + j) * 4 + jj] * (float)v0[j];
      }
#pragma unroll
      for (int j = 0; j < 8; ++j)
        Xd[shb][row][ch + j] = dtl * (acc[j] * sigm(acc[j]));
    }
    __syncthreads();

    // ---- compute ----
#pragma unroll 2
    for (int tt = 0; tt < kQH; ++tt) {
      const f4 xv = *(const f4*)&Xd[hb][tt][d0];
      const f4 a0 = ((const f4*)&Ad[hb][tt][sg8 * 8])[0];
      const f4 a1 = ((const f4*)&Ad[hb][tt][sg8 * 8])[1];
      const f4 b0 = ((const f4*)&Bd[hb][tt][sg8 * 8])[0];
      const f4 b1 = ((const f4*)&Bd[hb][tt][sg8 * 8])[1];
#pragma unroll
      for (int si = 0; si < 4; ++si) {
        h[si]     = a0[si] * h[si]     + b0[si] * xv;
        h[si + 4] = a1[si] * h[si + 4] + b1[si] * xv;
      }
    }
    __syncthreads();
  }

  if (t128 == 0) {     // tid 0 -> head 0, tid 128 -> head 1
    float s = 0.f;
    for (int t = 0; t < kQ; ++t) s += dts[shb][t];
    sdt[(bnp * 2 + shb) * kNC + c] = s;
  }

  float* hp = H + (((size_t)bn * kNC + c) * 64 + sg8 * 8) * 64 + d0;
#pragma unroll
  for (int si = 0; si < 8; ++si)
    *(f4*)&hp[(size_t)si * 64] = h[si];
}

// ---------------------------------------------------------------------------
// K4: chunk stitching IN-PLACE, scalar-d regrid. Unchanged from R12.
// ---------------------------------------------------------------------------
__global__ __launch_bounds__(256) void scan_pass2(
    float* __restrict__ H, const float* __restrict__ sdt,
    const float* __restrict__ negA) {
  const int bn = blockIdx.x >> 4;       // 64
  const int sq = blockIdx.x & 15;       // 16
  const int s  = sq * 4 + (threadIdx.x >> 6);
  const int d  = threadIdx.x & 63;
  const int n  = bn & 31;
  const float Aa = negA[n * 64 + s];
  float h = 0.f;
  for (int c = 0; c < kNC; ++c) {
    const size_t off = (((size_t)bn * kNC + c) * 64 + s) * 64 + d;
    const float ap = __expf(Aa * sdt[bn * kNC + c]);
    const float hl = H[off];   // local sums
    H[off] = h;                // overwrite with carry-in
    h = ap * h + hl;
  }
}

// ---------------------------------------------------------------------------
// K5: scan pass 3. R12 16sx2d structure + T14 register-prefetch: phase-1
// global loads issue BEFORE phase-0 compute; post-barrier staging is pure
// VALU+LDS-write. Z via reg path (LDS stays 40 KB). launch_bounds(256,4)
// protects 4-blocks/CU occupancy against the +~30 VGPR prefetch state.
// ---------------------------------------------------------------------------
__global__ __launch_bounds__(256, 4) void scan_pass3(
    const _Float16* __restrict__ proj16, const float* __restrict__ dtb,
    const float* __restrict__ negA, const float* __restrict__ conv_w,
    const float* __restrict__ conv_b, const float* __restrict__ H,
    const float* __restrict__ Dv, _Float16* __restrict__ yin) {
  __shared__ alignas(16) float Ad[2][kQH][64];     // 8 KB
  __shared__ alignas(16) float Bd[2][kQH][64];     // 8 KB
  __shared__ alignas(16) float Cd[2][kQH][64];     // 8 KB
  __shared__ alignas(16) float Xd[2][kQH][64];     // 8 KB (xdt f32)
  __shared__ alignas(16) _Float16 Xs[2][kQH][64];  // 2 KB (xsilu f16)
  __shared__ alignas(16) _Float16 Zd[2][kQH][64];  // 2 KB (raw z)
  const int tid  = threadIdx.x;
  const int g    = blockIdx.x;
  const int c    = g & (kNC - 1);
  const int bnp  = g >> 5;
  const int lane = tid & 63;
  const int w    = tid >> 6;
  const int hb   = w >> 1;
  const int wd   = w & 1;
  const int sg   = lane >> 4;
  const int dd   = lane & 15;
  const int bn   = bnp * 2 + hb;
  const int b    = bn >> 5, n = bn & 31;
  const int l0   = c * kQ;
  const int d0   = wd * 32 + dd * 2;
  const int t128 = tid & 127;
  const int shb  = tid >> 7;
  // staging-role constants
  const int sn  = (bnp * 2 + shb) & 31;
  const int sb  = (bnp * 2 + shb) >> 5;
  const int srw = t128 >> 3;
  const int sch = (t128 & 7) * 8;

  // h init from carry-in (registers, carried across both phases)
  f4 hA[4], hB[4];
  {
    const float* hp = H + (((size_t)bn * kNC + c) * 64 + sg * 16) * 64 + d0;
#pragma unroll
    for (int q = 0; q < 4; ++q)
#pragma unroll
      for (int i = 0; i < 4; ++i) {
        const f2 hv = *(const f2*)&hp[(size_t)(q * 4 + i) * 64];
        hA[q][i] = hv[0]; hB[q][i] = hv[1];
      }
  }
  const float Dn = Dv[n];
  _Float16* Yb = yin + (size_t)(b * kL + l0) * kDI + n * 64 + d0;

  f16x8 vb, vc, vz, vx[4];
  float dtl;

  auto load_ph = [&](int r0) {
    const int gl = l0 + r0 + srw;
    dtl = dtb[(size_t)(bnp * 2 + shb) * kL + gl];
    const _Float16* base = proj16 + (size_t)(sb * kL + gl) * kPROJW + sn * 64 + sch;
    vz = *(const f16x8*)(base + 2048);
    vb = *(const f16x8*)(base + 4096);
    vc = *(const f16x8*)(base + 6144);
#pragma unroll
    for (int jj = 0; jj < 4; ++jj) {
      const int r = gl - 3 + jj;
      if (r >= 0) {
        vx[jj] = *(const f16x8*)(proj16 + (size_t)(sb * kL + r) * kPROJW + sn * 64 + sch);
      } else {
        f16x8 zz = {};
        vx[jj] = zz;
      }
    }
  };

  auto stage_ph = [&]() {
    f4 blo, bhi, clo, chi;
    blo[0]=(float)vb[0]; blo[1]=(float)vb[1]; blo[2]=(float)vb[2]; blo[3]=(float)vb[3];
    bhi[0]=(float)vb[4]; bhi[1]=(float)vb[5]; bhi[2]=(float)vb[6]; bhi[3]=(float)vb[7];
    clo[0]=(float)vc[0]; clo[1]=(float)vc[1]; clo[2]=(float)vc[2]; clo[3]=(float)vc[3];
    chi[0]=(float)vc[4]; chi[1]=(float)vc[5]; chi[2]=(float)vc[6]; chi[3]=(float)vc[7];
    *(f4*)&Bd[shb][srw][sch]     = blo;
    *(f4*)&Bd[shb][srw][sch + 4] = bhi;
    *(f4*)&Cd[shb][srw][sch]     = clo;
    *(f4*)&Cd[shb][srw][sch + 4] = chi;
    *(f16x8*)&Zd[shb][srw][sch]  = vz;
#pragma unroll
    for (int j = 0; j < 8; ++j)
      Ad[shb][srw][sch + j] = __expf(negA[sn * 64 + sch + j] * dtl);
    float acc[8];
#pragma unroll
    for (int j = 0; j < 8; ++j) acc[j] = conv_b[sn * 64 + sch + j];
#pragma unroll
    for (int jj = 0; jj < 4; ++jj)
#pragma unroll
      for (int j = 0; j < 8; ++j)
        acc[j] += conv_w[(sn * 64 + sch + j) * 4 + jj] * (float)vx[jj][j];
    f16x8 xo;
#pragma unroll
    for (int j = 0; j < 8; ++j) {
      const float xs = acc[j] * sigm(acc[j]);
      xo[j] = (_Float16)xs;
      Xd[shb][srw][sch + j] = dtl * xs;
    }
    *(f16x8*)&Xs[shb][srw][sch] = xo;
  };

  auto compute_ph = [&](int r0) {
#pragma unroll 2
    for (int tt = 0; tt < kQH; ++tt) {
      const f2 xv = *(const f2*)&Xd[hb][tt][d0];
      const float x0 = xv[0], x1 = xv[1];
      f4 pvA = {}, pvB = {};
#pragma unroll
      for (int q = 0; q < 4; ++q) {
        const f4 a  = ((const f4*)&Ad[hb][tt][sg * 16])[q];
        const f4 bb = ((const f4*)&Bd[hb][tt][sg * 16])[q];
        const f4 cc = ((const f4*)&Cd[hb][tt][sg * 16])[q];
        hA[q] = a * hA[q] + bb * x0;
        hB[q] = a * hB[q] + bb * x1;
        pvA = pvA + cc * hA[q];
        pvB = pvB + cc * hB[q];
      }
      float pA = (pvA[0] + pvA[1]) + (pvA[2] + pvA[3]);
      float pB = (pvB[0] + pvB[1]) + (pvB[2] + pvB[3]);
      pA += __shfl_xor(pA, 16);
      pA += __shfl_xor(pA, 32);
      pB += __shfl_xor(pB, 16);
      pB += __shfl_xor(pB, 32);
      if (sg == 0) {
        const f16x2 zv = *(const f16x2*)&Zd[hb][tt][d0];
        const f16x2 xs = *(const f16x2*)&Xs[hb][tt][d0];
        const float z0 = (float)zv[0], z1 = (float)zv[1];
        const float y0 = (pA + Dn * (float)xs[0]) * (z0 * sigm(z0));
        const float y1 = (pB + Dn * (float)xs[1]) * (z1 * sigm(z1));
        f16x2 yv; yv[0] = (_Float16)y0; yv[1] = (_Float16)y1;
        *(f16x2*)&Yb[(size_t)(r0 + tt) * kDI] = yv;
      }
    }
  };

  // ---- pipelined 2-phase schedule ----
  load_ph(0);
  stage_ph();
  __syncthreads();
  load_ph(kQH);        // phase-1 loads in flight during phase-0 compute
  compute_ph(0);
  __syncthreads();     // vmcnt(0) drain: prefetch已 landed under compute
  stage_ph();
  __syncthreads();
  compute_ph(kQH);
}

// ---------------------------------------------------------------------------
// K6: out[2048,1024] f32 = yin @ Wo16^T. 64x64 tile, BK=32, dbuf prefetch,
// XCD swizzle (nwg=512), XOR-swizzle. Unchanged.
// ---------------------------------------------------------------------------
__global__ __launch_bounds__(256) void gemm_out(
    const _Float16* __restrict__ A, const _Float16* __restrict__ Bm,
    float* __restrict__ C) {
  __shared__ alignas(16) _Float16 As[2][64][32];
  __shared__ alignas(16) _Float16 Bs[2][64][32];
  const int tid  = threadIdx.x;
  const int lane = tid & 63;
  const int w    = tid >> 6;
  const int id   = blockIdx.x;
  const int sw   = (id & 7) * 64 + (id >> 3);    // XCD swizzle (nwg=512)
  const int m0   = (sw >> 4) * 64;               // 32 M-tiles
  const int n0   = (sw & 15) * 64;               // 16 N-tiles
  const int row  = tid >> 2;
  const int cc   = (tid & 3) * 8;                          // linear LDS chunk
  const int ccs  = (((lane & 3) ^ ((lane >> 3) & 3))) * 8; // swizzled global chunk
  const int wm   = (w & 1) * 32;
  const int wn   = (w >> 1) * 32;
  const int l16  = lane & 15;
  const int l4   = lane >> 4;
  const int rsw  = (l16 >> 1) & 3;                         // read-side XOR

  f4 acc[2][2] = {};

  auto stage = [&](int buf, int k0) {
    async_ld16(A + (size_t)(m0 + row) * kDI + (k0 + ccs), &As[buf][row][cc]);
    async_ld16(Bm + (size_t)(n0 + row) * kDI + (k0 + ccs), &Bs[buf][row][cc]);
  };
  auto compute = [&](int buf) {
    f16x8 af[2], bf[2];
#pragma unroll
    for (int t = 0; t < 2; ++t) {
      af[t] = *reinterpret_cast<const f16x8*>(&As[buf][wm + t * 16 + l16][(l4 ^ rsw) * 8]);
      bf[t] = *reinterpret_cast<const f16x8*>(&Bs[buf][wn + t * 16 + l16][(l4 ^ rsw) * 8]);
    }
#pragma unroll
    for (int i = 0; i < 2; ++i)
#pragma unroll
      for (int j = 0; j < 2; ++j)
        acc[i][j] = __builtin_amdgcn_mfma_f32_16x16x32_f16(af[i], bf[j], acc[i][j], 0, 0, 0);
  };

  stage(0, 0);
  __syncthreads();
  int cur = 0;
  for (int k0 = 0; k0 < kDI - 32; k0 += 32) {
    stage(cur ^ 1, k0 + 32);
    compute(cur);
    __syncthreads();
    cur ^= 1;
  }
  compute(cur);

  const int col = l16;
  const int r0  = l4 * 4;
#pragma unroll
  for (int i = 0; i < 2; ++i)
#pragma unroll
    for (int j = 0; j < 2; ++j) {
      const int gn = n0 + wn + j * 16 + col;
#pragma unroll
      for (int r = 0; r < 4; ++r) {
        const int gm = m0 + wm + i * 16 + r0 + r;
        C[(size_t)gm * kDM + gn] = acc[i][j][r];
      }
    }
}

// ---------------------------------------------------------------------------
extern "C" void kernel_launch(void* const* d_in, const int* in_sizes, int n_in,
                              void* d_out, int out_size, void* d_ws, size_t ws_size,
                              hipStream_t stream) {
  const float* x      = (const float*)d_in[0];
  const float* W_in   = (const float*)d_in[1];
  const float* conv_w = (const float*)d_in[2];
  const float* conv_b = (const float*)d_in[3];
  const float* A_log  = (const float*)d_in[4];
  const float* Dv     = (const float*)d_in[5];
  const float* dt_b   = (const float*)d_in[6];
  const float* W_out  = (const float*)d_in[7];
  float* out = (float*)d_out;

  char* p = (char*)d_ws;
  _Float16* proj16 = (_Float16*)p; p += (size_t)kBL * kPROJW * 2;   // 33.6 MB
  float* dtb   = (float*)p; p += (size_t)64 * kL * 4;
  float* negA  = (float*)p; p += 2048 * 4;
  float* sdt   = (float*)p; p += (size_t)64 * kNC * 4 + 3968;       // 8 KB + pad
  float* H     = (float*)p; p += (size_t)64 * kNC * 64 * 64 * 4;    // 33.6 MB (local sums -> carry-ins, in place)
  _Float16* yin  = (_Float16*)p; p += (size_t)kBL * kDI * 2;        // 8.4 MB
  _Float16* Wo16 = (_Float16*)p; p += (size_t)kDM * kDI * 2;        // 4.2 MB
  _Float16* x16  = (_Float16*)H;                    // alias (pre-scan phase)
  _Float16* Wi16 = x16 + (size_t)kBL * kDM;         // 16.8 MB, fits in H (33.6)

  prep_inputs<<<kCvtBlocks + kNegABlocks + kDtBlocks, 256, 0, stream>>>(
      x, W_in, W_out, A_log, dt_b, x16, Wi16, Wo16, negA, dtb);

  gemm1<<<(kBL / 128) * (kPROJW / 256), 512, 0, stream>>>(
      x16, Wi16, proj16, kBL, kPROJW, kDM);

  scan_pass1<<<(64 / 2) * kNC, 256, 0, stream>>>(proj16, dtb, negA, conv_w, conv_b, H, sdt);
  scan_pass2<<<64 * 16, 256, 0, stream>>>(H, sdt, negA);
  scan_pass3<<<(64 / 2) * kNC, 256, 0, stream>>>(proj16, dtb, negA, conv_w, conv_b, H, Dv, yin);

  gemm_out<<<(kBL / 64) * (kDM / 64), 256, 0, stream>>>(yin, Wo16, out);
}

// Round 14
// 267.259 us; speedup vs baseline: 1.1448x; 1.0053x over previous
//
#include <hip/hip_runtime.h>
#include <hip/hip_fp16.h>

namespace {
constexpr int kB  = 2;
constexpr int kL  = 1024;
constexpr int kDM = 1024;
constexpr int kDI = 2048;
constexpr int kPROJW = 8192;   // proj16 row: [x 0..2048 | z ..4096 | B ..6144 | C ..8192]
constexpr int kBL = 2048;
constexpr int kQ  = 32;        // chunk length
constexpr int kQH = 16;        // rows staged per phase
constexpr int kNC = 32;        // chunks per (b,n)
constexpr int kCvtX = kBL * kDM / 4;      // 524288 vec4
constexpr int kCvtW = 8192 * kDM / 4;     // 2097152 (WdtT pack removed)
constexpr int kCvtO = kDM * kDI / 4;      // 524288
constexpr int kCvtBlocks  = (kCvtX + kCvtW + kCvtO) / 256;  // 12288
constexpr int kNegABlocks = 8;
constexpr int kDtBlocks   = kBL / 4;      // 512 fused dt-gemm blocks
}

typedef float f4 __attribute__((ext_vector_type(4)));
typedef float f2 __attribute__((ext_vector_type(2)));
typedef _Float16 f16x8 __attribute__((ext_vector_type(8)));
typedef _Float16 f16x4 __attribute__((ext_vector_type(4)));
typedef _Float16 f16x2 __attribute__((ext_vector_type(2)));

__device__ __forceinline__ void async_ld16(const void* g, void* l) {
  __builtin_amdgcn_global_load_lds(
      (const __attribute__((address_space(1))) void*)g,
      (__attribute__((address_space(3))) void*)l, 16, 0, 0);
}

__device__ __forceinline__ float sigm(float v) {
  return __builtin_amdgcn_rcpf(1.f + __expf(-v));   // 1-instr rcp vs IEEE div
}

// ---------------------------------------------------------------------------
// K1 (fused): f32->f16 cvt of x / W_in / W_out + negA + dt_gemm.
// ---------------------------------------------------------------------------
__global__ __launch_bounds__(256) void prep_inputs(
    const float* __restrict__ x, const float* __restrict__ W_in,
    const float* __restrict__ W_out, const float* __restrict__ A_log,
    const float* __restrict__ dt_bias,
    _Float16* __restrict__ x16, _Float16* __restrict__ Wi16,
    _Float16* __restrict__ Wo16, float* __restrict__ negA,
    float* __restrict__ dtb) {
  __shared__ alignas(16) float Xs2[4][1024];   // 16 KB   (dt path)
  __shared__ alignas(16) float Wk[128][33];    // 16.9 KB (dt path, transposed tile)
  __shared__ float Ps[4][8][32];               // 4 KB    (dt path)
  const int bid = blockIdx.x;
  const int tid = threadIdx.x;
  if (bid < kCvtBlocks) {
    int i = bid * 256 + tid;
    if (i < kCvtX) {
      const f4 v = ((const f4*)x)[i];
      f16x4 o; o[0]=(_Float16)v[0]; o[1]=(_Float16)v[1]; o[2]=(_Float16)v[2]; o[3]=(_Float16)v[3];
      ((f16x4*)x16)[i] = o;
    } else if (i < kCvtX + kCvtW) {
      i -= kCvtX;
      const int row = i >> 8;        // [0, 8192)
      const int cv  = i & 255;
      int srow;
      if (row < 4096)      srow = row;
      else if (row < 6144) { const int m = row - 4096; srow = 4096 + (m >> 6) * 129 + (m & 63); }
      else                 { const int m = row - 6144; srow = 4096 + (m >> 6) * 129 + 64 + (m & 63); }
      const f4 v = ((const f4*)(W_in + (size_t)srow * kDM))[cv];
      f16x4 o; o[0]=(_Float16)v[0]; o[1]=(_Float16)v[1]; o[2]=(_Float16)v[2]; o[3]=(_Float16)v[3];
      ((f16x4*)(Wi16 + (size_t)row * kDM))[cv] = o;
    } else {
      i -= kCvtX + kCvtW;
      const f4 v = ((const f4*)W_out)[i];
      f16x4 o; o[0]=(_Float16)v[0]; o[1]=(_Float16)v[1]; o[2]=(_Float16)v[2]; o[3]=(_Float16)v[3];
      ((f16x4*)Wo16)[i] = o;
    }
  } else if (bid < kCvtBlocks + kNegABlocks) {
    const int i = (bid - kCvtBlocks) * 256 + tid;
    if (i < 2048) negA[i] = -__expf(A_log[i]);
  } else {
    // ---- dt_gemm: dtb = softplus(x @ Wdt^T + bias), f32 exact ----
    const int gm0 = (bid - kCvtBlocks - kNegABlocks) * 4;
#pragma unroll
    for (int q = 0; q < 4; ++q)
      *(f4*)&Xs2[q][tid * 4] = *(const f4*)(x + (size_t)(gm0 + q) * kDM + tid * 4);
    const int h    = tid & 31;
    const int sl   = tid >> 5;
    const int wh   = tid >> 3;          // W dt-row 0..31
    const int part = tid & 7;
    const size_t srow = (size_t)(4096 + wh * 129 + 128) * kDM;
    float p0 = 0.f, p1 = 0.f, p2 = 0.f, p3 = 0.f;
    __syncthreads();
    for (int kt = 0; kt < 8; ++kt) {
      // load+transpose W tile: 32 rows x 128 k -> Wk[k][h]
#pragma unroll
      for (int j = 0; j < 4; ++j) {
        const f4 v = *(const f4*)(W_in + srow + kt * 128 + part * 16 + j * 4);
#pragma unroll
        for (int e = 0; e < 4; ++e) Wk[part * 16 + j * 4 + e][wh] = v[e];
      }
      __syncthreads();
      const int kb = kt * 128 + sl * 16;
#pragma unroll
      for (int i2 = 0; i2 < 16; ++i2) {
        const float wv = Wk[sl * 16 + i2][h];
        p0 = fmaf(Xs2[0][kb + i2], wv, p0);
        p1 = fmaf(Xs2[1][kb + i2], wv, p1);
        p2 = fmaf(Xs2[2][kb + i2], wv, p2);
        p3 = fmaf(Xs2[3][kb + i2], wv, p3);
      }
      __syncthreads();
    }
    Ps[0][sl][h] = p0; Ps[1][sl][h] = p1; Ps[2][sl][h] = p2; Ps[3][sl][h] = p3;
    __syncthreads();
    if (tid < 128) {
      const int r = tid >> 5, hh = tid & 31;
      float v = 0.f;
#pragma unroll
      for (int s2 = 0; s2 < 8; ++s2) v += Ps[r][s2][hh];
      const float dtp = v + dt_bias[hh];
      const float dt  = (dtp > 20.f) ? dtp : log1pf(__expf(dtp));
      const int gm = gm0 + r;
      dtb[(size_t)((gm >> 10) * 32 + hh) * kL + (gm & 1023)] = dt;
    }
  }
}

// ---------------------------------------------------------------------------
// K2: f16 GEMM, BM=128 x BN=256, 512 thr, BK=32. NEW: 3-buffer 2-deep
// pipeline with counted vmcnt (T4) + raw s_barrier + setprio (T5).
// Tile t+2's loads issue at iter t -> 2 compute phases to land; vmcnt(3)
// (never 0 mid-loop) keeps the next prefetch in flight across barriers.
// Per-wave vmcnt(3) before barrier => own tile-(t+1) loads landed; barrier
// => all waves' contributions resident. LDS 72 KB -> 2 blocks/CU (= grid
// residency, unchanged). T2 XOR-swizzle + XCD swizzle kept.
// ---------------------------------------------------------------------------
__global__ __launch_bounds__(512) void gemm1(
    const _Float16* __restrict__ A, const _Float16* __restrict__ Bm,
    _Float16* __restrict__ C, int M, int N, int K) {
  __shared__ alignas(16) _Float16 As[3][128][32];
  __shared__ alignas(16) _Float16 Bs[3][256][32];
  const int tid  = threadIdx.x;      // 0..511
  const int lane = tid & 63;
  const int w    = tid >> 6;         // 0..7
  const int id   = blockIdx.x;
  const int sw   = (id & 7) * 64 + (id >> 3);    // XCD swizzle (nwg=512)
  const int m0   = (sw & 15) * 128;              // 16 M tiles
  const int n0   = (sw >> 4) * 256;              // 32 N tiles
  const int ar   = tid >> 2;                     // staging row 0..127
  const int cc   = (tid & 3) * 8;                            // linear LDS chunk
  const int ccs  = (((tid & 3) ^ ((tid >> 3) & 3))) * 8;     // swizzled global chunk
  const int wm   = (w & 1) * 64;                 // wave M offset (2 x 64)
  const int wn   = (w >> 1) * 64;                // wave N offset (4 x 64)
  const int l16  = lane & 15;
  const int l4   = lane >> 4;
  const int rsw  = (l16 >> 1) & 3;               // read-side XOR key

  f4 acc[4][4] = {};

  auto stage = [&](int buf, int k0) {
    async_ld16(A  + (size_t)(m0 + ar) * K + (k0 + ccs), &As[buf][ar][cc]);
    async_ld16(Bm + (size_t)(n0 + ar) * K + (k0 + ccs), &Bs[buf][ar][cc]);
    async_ld16(Bm + (size_t)(n0 + 128 + ar) * K + (k0 + ccs), &Bs[buf][128 + ar][cc]);
  };
  auto compute = [&](int buf) {
    f16x8 af[4], bf[4];
#pragma unroll
    for (int t = 0; t < 4; ++t) {
      af[t] = *reinterpret_cast<const f16x8*>(&As[buf][wm + t * 16 + l16][(l4 ^ rsw) * 8]);
      bf[t] = *reinterpret_cast<const f16x8*>(&Bs[buf][wn + t * 16 + l16][(l4 ^ rsw) * 8]);
    }
    __builtin_amdgcn_s_setprio(1);
#pragma unroll
    for (int i = 0; i < 4; ++i)
#pragma unroll
      for (int j = 0; j < 4; ++j)
        acc[i][j] = __builtin_amdgcn_mfma_f32_16x16x32_f16(af[i], bf[j], acc[i][j], 0, 0, 0);
    __builtin_amdgcn_s_setprio(0);
  };

  const int nt = K >> 5;           // 32 K-tiles
  stage(0, 0);
  stage(1, 32);
  asm volatile("s_waitcnt vmcnt(3)" ::: "memory");   // tile 0 landed
  __builtin_amdgcn_s_barrier();
  int buf = 0;
  for (int t = 0; t < nt; ++t) {
    const bool pre = (t + 2) < nt;
    if (pre) stage((buf + 2 >= 3) ? buf - 1 : buf + 2, (t + 2) << 5);
    compute(buf);
    if (t < nt - 1) {
      if (pre) asm volatile("s_waitcnt vmcnt(3)" ::: "memory");  // tile t+1 landed
      else     asm volatile("s_waitcnt vmcnt(0)" ::: "memory");  // drain tail
      __builtin_amdgcn_s_barrier();
    }
    buf = (buf + 1 == 3) ? 0 : buf + 1;
  }

  const int col = l16;      // C/D: col = lane&15, row = (lane>>4)*4 + reg
  const int r0  = l4 * 4;
#pragma unroll
  for (int i = 0; i < 4; ++i)
#pragma unroll
    for (int j = 0; j < 4; ++j) {
      const int gn = n0 + wn + j * 16 + col;
#pragma unroll
      for (int r = 0; r < 4; ++r) {
        const int gm = m0 + wm + i * 16 + r0 + r;
        C[(size_t)gm * N + gn] = (_Float16)acc[i][j][r];
      }
    }
}

// ---------------------------------------------------------------------------
// K3: scan pass 1. 2 heads per 256-thr block, 8s x 4d lane map. Unchanged.
// ---------------------------------------------------------------------------
__global__ __launch_bounds__(256) void scan_pass1(
    const _Float16* __restrict__ proj16, const float* __restrict__ dtb,
    const float* __restrict__ negA, const float* __restrict__ conv_w,
    const float* __restrict__ conv_b, float* __restrict__ H,
    float* __restrict__ sdt) {
  __shared__ alignas(16) float Ad[2][kQH][64];   // 8 KB
  __shared__ alignas(16) float Bd[2][kQH][64];   // 8 KB
  __shared__ alignas(16) float Xd[2][kQH][64];   // 8 KB (xdt f32)
  __shared__ float dts[2][kQ];
  const int tid  = threadIdx.x;
  const int g    = blockIdx.x;
  const int c    = g & (kNC - 1);
  const int bnp  = g >> 5;
  const int lane = tid & 63;
  const int w    = tid >> 6;
  const int hb   = w >> 1;
  const int wd   = w & 1;
  const int sg8  = lane >> 3;      // s-group (8 s each)
  const int dd   = lane & 7;
  const int bn   = bnp * 2 + hb;
  const int l0   = c * kQ;
  const int d0   = wd * 32 + dd * 4;
  const int t128 = tid & 127;
  const int shb  = tid >> 7;   // staging: which head this thread serves

  f4 h[8] = {};

  for (int p = 0; p < 2; ++p) {
    const int r0 = p * kQH;
    // ---- stage (128 thr per head): row = t128>>3, 8-ch slice ----
    {
      const int sn  = (bnp * 2 + shb) & 31;
      const int sb  = (bnp * 2 + shb) >> 5;
      const int row = t128 >> 3;
      const int ch  = (t128 & 7) * 8;
      const int gl  = l0 + r0 + row;
      const float dtl = dtb[(size_t)(bnp * 2 + shb) * kL + gl];
      if ((t128 & 7) == 0) dts[shb][r0 + row] = dtl;
      // B: f16 -> f32
      const f16x8 vb = *(const f16x8*)(proj16 +
          (size_t)(sb * kL + gl) * kPROJW + 4096 + sn * 64 + ch);
      f4 blo, bhi;
      blo[0]=(float)vb[0]; blo[1]=(float)vb[1]; blo[2]=(float)vb[2]; blo[3]=(float)vb[3];
      bhi[0]=(float)vb[4]; bhi[1]=(float)vb[5]; bhi[2]=(float)vb[6]; bhi[3]=(float)vb[7];
      *(f4*)&Bd[shb][row][ch]     = blo;
      *(f4*)&Bd[shb][row][ch + 4] = bhi;
      // A: exp
#pragma unroll
      for (int j = 0; j < 8; ++j)
        Ad[shb][row][ch + j] = __expf(negA[sn * 64 + ch + j] * dtl);
      // conv + silu -> xdt (f32)
      float acc[8];
#pragma unroll
      for (int j = 0; j < 8; ++j) acc[j] = conv_b[sn * 64 + ch + j];
#pragma unroll
      for (int jj = 0; jj < 4; ++jj) {
        const int r = gl - 3 + jj;
        if (r < 0) continue;
        const f16x8 v0 = *(const f16x8*)(proj16 + (size_t)(sb * kL + r) * kPROJW + sn * 64 + ch);
#pragma unroll
        for (int j = 0; j < 8; ++j)
          acc[j] += conv_w[(sn * 64 + ch + j) * 4 + jj] * (float)v0[j];
      }
#pragma unroll
      for (int j = 0; j < 8; ++j)
        Xd[shb][row][ch + j] = dtl * (acc[j] * sigm(acc[j]));
    }
    __syncthreads();

    // ---- compute ----
#pragma unroll 2
    for (int tt = 0; tt < kQH; ++tt) {
      const f4 xv = *(const f4*)&Xd[hb][tt][d0];
      const f4 a0 = ((const f4*)&Ad[hb][tt][sg8 * 8])[0];
      const f4 a1 = ((const f4*)&Ad[hb][tt][sg8 * 8])[1];
      const f4 b0 = ((const f4*)&Bd[hb][tt][sg8 * 8])[0];
      const f4 b1 = ((const f4*)&Bd[hb][tt][sg8 * 8])[1];
#pragma unroll
      for (int si = 0; si < 4; ++si) {
        h[si]     = a0[si] * h[si]     + b0[si] * xv;
        h[si + 4] = a1[si] * h[si + 4] + b1[si] * xv;
      }
    }
    __syncthreads();
  }

  if (t128 == 0) {     // tid 0 -> head 0, tid 128 -> head 1
    float s = 0.f;
    for (int t = 0; t < kQ; ++t) s += dts[shb][t];
    sdt[(bnp * 2 + shb) * kNC + c] = s;
  }

  float* hp = H + (((size_t)bn * kNC + c) * 64 + sg8 * 8) * 64 + d0;
#pragma unroll
  for (int si = 0; si < 8; ++si)
    *(f4*)&hp[(size_t)si * 64] = h[si];
}

// ---------------------------------------------------------------------------
// K4: chunk stitching IN-PLACE, scalar-d regrid. Unchanged.
// ---------------------------------------------------------------------------
__global__ __launch_bounds__(256) void scan_pass2(
    float* __restrict__ H, const float* __restrict__ sdt,
    const float* __restrict__ negA) {
  const int bn = blockIdx.x >> 4;       // 64
  const int sq = blockIdx.x & 15;       // 16
  const int s  = sq * 4 + (threadIdx.x >> 6);
  const int d  = threadIdx.x & 63;
  const int n  = bn & 31;
  const float Aa = negA[n * 64 + s];
  float h = 0.f;
  for (int c = 0; c < kNC; ++c) {
    const size_t off = (((size_t)bn * kNC + c) * 64 + s) * 64 + d;
    const float ap = __expf(Aa * sdt[bn * kNC + c]);
    const float hl = H[off];   // local sums
    H[off] = h;                // overwrite with carry-in
    h = ap * h + hl;
  }
}

// ---------------------------------------------------------------------------
// K5: scan pass 3. 16sx2d + T14 register-prefetch. Unchanged from R13.
// ---------------------------------------------------------------------------
__global__ __launch_bounds__(256, 4) void scan_pass3(
    const _Float16* __restrict__ proj16, const float* __restrict__ dtb,
    const float* __restrict__ negA, const float* __restrict__ conv_w,
    const float* __restrict__ conv_b, const float* __restrict__ H,
    const float* __restrict__ Dv, _Float16* __restrict__ yin) {
  __shared__ alignas(16) float Ad[2][kQH][64];     // 8 KB
  __shared__ alignas(16) float Bd[2][kQH][64];     // 8 KB
  __shared__ alignas(16) float Cd[2][kQH][64];     // 8 KB
  __shared__ alignas(16) float Xd[2][kQH][64];     // 8 KB (xdt f32)
  __shared__ alignas(16) _Float16 Xs[2][kQH][64];  // 2 KB (xsilu f16)
  __shared__ alignas(16) _Float16 Zd[2][kQH][64];  // 2 KB (raw z)
  const int tid  = threadIdx.x;
  const int g    = blockIdx.x;
  const int c    = g & (kNC - 1);
  const int bnp  = g >> 5;
  const int lane = tid & 63;
  const int w    = tid >> 6;
  const int hb   = w >> 1;
  const int wd   = w & 1;
  const int sg   = lane >> 4;
  const int dd   = lane & 15;
  const int bn   = bnp * 2 + hb;
  const int b    = bn >> 5, n = bn & 31;
  const int l0   = c * kQ;
  const int d0   = wd * 32 + dd * 2;
  const int t128 = tid & 127;
  const int shb  = tid >> 7;
  // staging-role constants
  const int sn  = (bnp * 2 + shb) & 31;
  const int sb  = (bnp * 2 + shb) >> 5;
  const int srw = t128 >> 3;
  const int sch = (t128 & 7) * 8;

  // h init from carry-in (registers, carried across both phases)
  f4 hA[4], hB[4];
  {
    const float* hp = H + (((size_t)bn * kNC + c) * 64 + sg * 16) * 64 + d0;
#pragma unroll
    for (int q = 0; q < 4; ++q)
#pragma unroll
      for (int i = 0; i < 4; ++i) {
        const f2 hv = *(const f2*)&hp[(size_t)(q * 4 + i) * 64];
        hA[q][i] = hv[0]; hB[q][i] = hv[1];
      }
  }
  const float Dn = Dv[n];
  _Float16* Yb = yin + (size_t)(b * kL + l0) * kDI + n * 64 + d0;

  f16x8 vb, vc, vz, vx[4];
  float dtl;

  auto load_ph = [&](int r0) {
    const int gl = l0 + r0 + srw;
    dtl = dtb[(size_t)(bnp * 2 + shb) * kL + gl];
    const _Float16* base = proj16 + (size_t)(sb * kL + gl) * kPROJW + sn * 64 + sch;
    vz = *(const f16x8*)(base + 2048);
    vb = *(const f16x8*)(base + 4096);
    vc = *(const f16x8*)(base + 6144);
#pragma unroll
    for (int jj = 0; jj < 4; ++jj) {
      const int r = gl - 3 + jj;
      if (r >= 0) {
        vx[jj] = *(const f16x8*)(proj16 + (size_t)(sb * kL + r) * kPROJW + sn * 64 + sch);
      } else {
        f16x8 zz = {};
        vx[jj] = zz;
      }
    }
  };

  auto stage_ph = [&]() {
    f4 blo, bhi, clo, chi;
    blo[0]=(float)vb[0]; blo[1]=(float)vb[1]; blo[2]=(float)vb[2]; blo[3]=(float)vb[3];
    bhi[0]=(float)vb[4]; bhi[1]=(float)vb[5]; bhi[2]=(float)vb[6]; bhi[3]=(float)vb[7];
    clo[0]=(float)vc[0]; clo[1]=(float)vc[1]; clo[2]=(float)vc[2]; clo[3]=(float)vc[3];
    chi[0]=(float)vc[4]; chi[1]=(float)vc[5]; chi[2]=(float)vc[6]; chi[3]=(float)vc[7];
    *(f4*)&Bd[shb][srw][sch]     = blo;
    *(f4*)&Bd[shb][srw][sch + 4] = bhi;
    *(f4*)&Cd[shb][srw][sch]     = clo;
    *(f4*)&Cd[shb][srw][sch + 4] = chi;
    *(f16x8*)&Zd[shb][srw][sch]  = vz;
#pragma unroll
    for (int j = 0; j < 8; ++j)
      Ad[shb][srw][sch + j] = __expf(negA[sn * 64 + sch + j] * dtl);
    float acc[8];
#pragma unroll
    for (int j = 0; j < 8; ++j) acc[j] = conv_b[sn * 64 + sch + j];
#pragma unroll
    for (int jj = 0; jj < 4; ++jj)
#pragma unroll
      for (int j = 0; j < 8; ++j)
        acc[j] += conv_w[(sn * 64 + sch + j) * 4 + jj] * (float)vx[jj][j];
    f16x8 xo;
#pragma unroll
    for (int j = 0; j < 8; ++j) {
      const float xs = acc[j] * sigm(acc[j]);
      xo[j] = (_Float16)xs;
      Xd[shb][srw][sch + j] = dtl * xs;
    }
    *(f16x8*)&Xs[shb][srw][sch] = xo;
  };

  auto compute_ph = [&](int r0) {
#pragma unroll 2
    for (int tt = 0; tt < kQH; ++tt) {
      const f2 xv = *(const f2*)&Xd[hb][tt][d0];
      const float x0 = xv[0], x1 = xv[1];
      f4 pvA = {}, pvB = {};
#pragma unroll
      for (int q = 0; q < 4; ++q) {
        const f4 a  = ((const f4*)&Ad[hb][tt][sg * 16])[q];
        const f4 bb = ((const f4*)&Bd[hb][tt][sg * 16])[q];
        const f4 cc = ((const f4*)&Cd[hb][tt][sg * 16])[q];
        hA[q] = a * hA[q] + bb * x0;
        hB[q] = a * hB[q] + bb * x1;
        pvA = pvA + cc * hA[q];
        pvB = pvB + cc * hB[q];
      }
      float pA = (pvA[0] + pvA[1]) + (pvA[2] + pvA[3]);
      float pB = (pvB[0] + pvB[1]) + (pvB[2] + pvB[3]);
      pA += __shfl_xor(pA, 16);
      pA += __shfl_xor(pA, 32);
      pB += __shfl_xor(pB, 16);
      pB += __shfl_xor(pB, 32);
      if (sg == 0) {
        const f16x2 zv = *(const f16x2*)&Zd[hb][tt][d0];
        const f16x2 xs = *(const f16x2*)&Xs[hb][tt][d0];
        const float z0 = (float)zv[0], z1 = (float)zv[1];
        const float y0 = (pA + Dn * (float)xs[0]) * (z0 * sigm(z0));
        const float y1 = (pB + Dn * (float)xs[1]) * (z1 * sigm(z1));
        f16x2 yv; yv[0] = (_Float16)y0; yv[1] = (_Float16)y1;
        *(f16x2*)&Yb[(size_t)(r0 + tt) * kDI] = yv;
      }
    }
  };

  // ---- pipelined 2-phase schedule ----
  load_ph(0);
  stage_ph();
  __syncthreads();
  load_ph(kQH);        // phase-1 loads in flight during phase-0 compute
  compute_ph(0);
  __syncthreads();     // prefetch landed under compute
  stage_ph();
  __syncthreads();
  compute_ph(kQH);
}

// ---------------------------------------------------------------------------
// K6: out[2048,1024] f32 = yin @ Wo16^T. 64x64 tile, BK=32, dbuf prefetch,
// XCD swizzle (nwg=512), XOR-swizzle. Unchanged.
// ---------------------------------------------------------------------------
__global__ __launch_bounds__(256) void gemm_out(
    const _Float16* __restrict__ A, const _Float16* __restrict__ Bm,
    float* __restrict__ C) {
  __shared__ alignas(16) _Float16 As[2][64][32];
  __shared__ alignas(16) _Float16 Bs[2][64][32];
  const int tid  = threadIdx.x;
  const int lane = tid & 63;
  const int w    = tid >> 6;
  const int id   = blockIdx.x;
  const int sw   = (id & 7) * 64 + (id >> 3);    // XCD swizzle (nwg=512)
  const int m0   = (sw >> 4) * 64;               // 32 M-tiles
  const int n0   = (sw & 15) * 64;               // 16 N-tiles
  const int row  = tid >> 2;
  const int cc   = (tid & 3) * 8;                          // linear LDS chunk
  const int ccs  = (((lane & 3) ^ ((lane >> 3) & 3))) * 8; // swizzled global chunk
  const int wm   = (w & 1) * 32;
  const int wn   = (w >> 1) * 32;
  const int l16  = lane & 15;
  const int l4   = lane >> 4;
  const int rsw  = (l16 >> 1) & 3;                         // read-side XOR

  f4 acc[2][2] = {};

  auto stage = [&](int buf, int k0) {
    async_ld16(A + (size_t)(m0 + row) * kDI + (k0 + ccs), &As[buf][row][cc]);
    async_ld16(Bm + (size_t)(n0 + row) * kDI + (k0 + ccs), &Bs[buf][row][cc]);
  };
  auto compute = [&](int buf) {
    f16x8 af[2], bf[2];
#pragma unroll
    for (int t = 0; t < 2; ++t) {
      af[t] = *reinterpret_cast<const f16x8*>(&As[buf][wm + t * 16 + l16][(l4 ^ rsw) * 8]);
      bf[t] = *reinterpret_cast<const f16x8*>(&Bs[buf][wn + t * 16 + l16][(l4 ^ rsw) * 8]);
    }
#pragma unroll
    for (int i = 0; i < 2; ++i)
#pragma unroll
      for (int j = 0; j < 2; ++j)
        acc[i][j] = __builtin_amdgcn_mfma_f32_16x16x32_f16(af[i], bf[j], acc[i][j], 0, 0, 0);
  };

  stage(0, 0);
  __syncthreads();
  int cur = 0;
  for (int k0 = 0; k0 < kDI - 32; k0 += 32) {
    stage(cur ^ 1, k0 + 32);
    compute(cur);
    __syncthreads();
    cur ^= 1;
  }
  compute(cur);

  const int col = l16;
  const int r0  = l4 * 4;
#pragma unroll
  for (int i = 0; i < 2; ++i)
#pragma unroll
    for (int j = 0; j < 2; ++j) {
      const int gn = n0 + wn + j * 16 + col;
#pragma unroll
      for (int r = 0; r < 4; ++r) {
        const int gm = m0 + wm + i * 16 + r0 + r;
        C[(size_t)gm * kDM + gn] = acc[i][j][r];
      }
    }
}

// ---------------------------------------------------------------------------
extern "C" void kernel_launch(void* const* d_in, const int* in_sizes, int n_in,
                              void* d_out, int out_size, void* d_ws, size_t ws_size,
                              hipStream_t stream) {
  const float* x      = (const float*)d_in[0];
  const float* W_in   = (const float*)d_in[1];
  const float* conv_w = (const float*)d_in[2];
  const float* conv_b = (const float*)d_in[3];
  const float* A_log  = (const float*)d_in[4];
  const float* Dv     = (const float*)d_in[5];
  const float* dt_b   = (const float*)d_in[6];
  const float* W_out  = (const float*)d_in[7];
  float* out = (float*)d_out;

  char* p = (char*)d_ws;
  _Float16* proj16 = (_Float16*)p; p += (size_t)kBL * kPROJW * 2;   // 33.6 MB
  float* dtb   = (float*)p; p += (size_t)64 * kL * 4;
  float* negA  = (float*)p; p += 2048 * 4;
  float* sdt   = (float*)p; p += (size_t)64 * kNC * 4 + 3968;       // 8 KB + pad
  float* H     = (float*)p; p += (size_t)64 * kNC * 64 * 64 * 4;    // 33.6 MB (local sums -> carry-ins, in place)
  _Float16* yin  = (_Float16*)p; p += (size_t)kBL * kDI * 2;        // 8.4 MB
  _Float16* Wo16 = (_Float16*)p; p += (size_t)kDM * kDI * 2;        // 4.2 MB
  _Float16* x16  = (_Float16*)H;                    // alias (pre-scan phase)
  _Float16* Wi16 = x16 + (size_t)kBL * kDM;         // 16.8 MB, fits in H (33.6)

  prep_inputs<<<kCvtBlocks + kNegABlocks + kDtBlocks, 256, 0, stream>>>(
      x, W_in, W_out, A_log, dt_b, x16, Wi16, Wo16, negA, dtb);

  gemm1<<<(kBL / 128) * (kPROJW / 256), 512, 0, stream>>>(
      x16, Wi16, proj16, kBL, kPROJW, kDM);

  scan_pass1<<<(64 / 2) * kNC, 256, 0, stream>>>(proj16, dtb, negA, conv_w, conv_b, H, sdt);
  scan_pass2<<<64 * 16, 256, 0, stream>>>(H, sdt, negA);
  scan_pass3<<<(64 / 2) * kNC, 256, 0, stream>>>(proj16, dtb, negA, conv_w, conv_b, H, Dv, yin);

  gemm_out<<<(kBL / 64) * (kDM / 64), 256, 0, stream>>>(yin, Wo16, out);
}